// Round 4
// baseline (205.237 us; speedup 1.0000x reference)
//
#include <hip/hip_runtime.h>
#include <hip/hip_bf16.h>
#include <stdint.h>

#define TSEQ 4096
#define DM   1024
#define NH   16
#define HD   64
#define NQKV 3072

typedef unsigned short u16;
typedef unsigned int   u32;
typedef __attribute__((ext_vector_type(8)))  short bf16x8;
typedef __attribute__((ext_vector_type(4)))  float f32x4;
typedef __attribute__((ext_vector_type(16))) float f32x16;
typedef __attribute__((ext_vector_type(4)))  int   i32x4;

static __device__ __forceinline__ u16 f2bf(float f) {
  u32 u = __float_as_uint(f);
  u32 r = (u + 0x7FFFu + ((u >> 16) & 1u)) >> 16;   // RNE
  return (u16)r;
}
static __device__ __forceinline__ float bf2f(u16 u) {
  return __uint_as_float(((u32)u) << 16);
}
static __device__ __forceinline__ u32 cvt_pk_bf16(float lo, float hi) {
  u32 r;
  asm("v_cvt_pk_bf16_f32 %0, %1, %2" : "=v"(r) : "v"(lo), "v"(hi));
  return r;
}

#define GLL16(g, l) __builtin_amdgcn_global_load_lds( \
    (const __attribute__((address_space(1))) u32*)(g), \
    (__attribute__((address_space(3))) u32*)(l), 16, 0, 0)

// ---------------- cast fp32 -> bf16 (4 elems/thread) ----------------
__global__ void cast_kernel(const float* __restrict__ in, u16* __restrict__ out, int n4) {
  int i = blockIdx.x * 256 + threadIdx.x;
  if (i >= n4) return;
  float4 v = ((const float4*)in)[i];
  ushort4 o;
  o.x = f2bf(v.x); o.y = f2bf(v.y); o.z = f2bf(v.z); o.w = f2bf(v.w);
  ((ushort4*)out)[i] = o;
}

// ---------------- RoPE sin/cos table [T][32] ----------------
__global__ void rope_table(float* __restrict__ sT, float* __restrict__ cT) {
  int i = blockIdx.x * 256 + threadIdx.x;   // t*32 + j
  int t = i >> 5, j = i & 31;
  float inv = exp2f((float)j * (-13.287712379549449f / 32.0f)); // 10000^(-j/32)
  float ang = (float)t * inv;
  sT[i] = sinf(ang);
  cT[i] = cosf(ang);
}

// ---------------- GEMM C[M,N] = A[M,K] * B[N,K]^T (bf16 in, fp32 acc) --------
template<int WRITE_BF16>
__global__ __launch_bounds__(256) void gemm_bt(const u16* __restrict__ A,
                                               const u16* __restrict__ B,
                                               void* __restrict__ Cout,
                                               int M, int N, int K)
{
  __shared__ __align__(16) u16 As[128 * 32];
  __shared__ __align__(16) u16 Bs[128 * 32];
  const int tid  = threadIdx.x;
  const int wave = tid >> 6, lane = tid & 63;
  const int l15  = lane & 15, lh = lane >> 4;
  const int wr   = wave >> 1, wc = wave & 1;

  const int nwg = gridDim.x * gridDim.y;
  int lin = blockIdx.y * gridDim.x + blockIdx.x;
  lin = (lin & 7) * (nwg >> 3) + (lin >> 3);          // nwg % 8 == 0
  const size_t bm = (size_t)(lin / gridDim.x);
  const size_t bn = (size_t)(lin % gridDim.x);

  f32x4 acc[4][4] = {};

  const u16* Ab = A + bm * 128 * (size_t)K;
  const u16* Bb = B + bn * 128 * (size_t)K;

  for (int k0 = 0; k0 < K; k0 += 32) {
    __syncthreads();
#pragma unroll
    for (int j = 0; j < 2; ++j) {
      const int ch = j * 4 + wave;            // 8 chunks of 1024B per tile
      const int e  = ch * 512 + lane * 8;     // element within tile (row-major [128][32])
      const int r  = e >> 5, c = e & 31;
      GLL16(Ab + (size_t)r * K + k0 + c, As + ch * 512);
      GLL16(Bb + (size_t)r * K + k0 + c, Bs + ch * 512);
    }
    asm volatile("s_waitcnt vmcnt(0)" ::: "memory");
    __syncthreads();

    bf16x8 af[4], bfr[4];
#pragma unroll
    for (int m = 0; m < 4; ++m)
      af[m] = *(const bf16x8*)(As + (wr * 64 + m * 16 + l15) * 32 + lh * 8);
#pragma unroll
    for (int n = 0; n < 4; ++n)
      bfr[n] = *(const bf16x8*)(Bs + (wc * 64 + n * 16 + l15) * 32 + lh * 8);
#pragma unroll
    for (int m = 0; m < 4; ++m)
#pragma unroll
      for (int n = 0; n < 4; ++n)
        acc[m][n] = __builtin_amdgcn_mfma_f32_16x16x32_bf16(af[m], bfr[n], acc[m][n], 0, 0, 0);
  }

#pragma unroll
  for (int m = 0; m < 4; ++m)
#pragma unroll
    for (int n = 0; n < 4; ++n)
#pragma unroll
      for (int r = 0; r < 4; ++r) {
        size_t row = bm * 128 + wr * 64 + m * 16 + lh * 4 + r;
        size_t col = bn * 128 + wc * 64 + n * 16 + l15;
        float v = acc[m][n][r];
        if (WRITE_BF16) ((u16*)Cout)[row * N + col] = f2bf(v);
        else            ((float*)Cout)[row * N + col] = v;
      }
}

// ---------------- RoPE + head-split into MFMA-fragment-tiled layouts --------
// Q/K: frag idx = (((h*128 + (t>>5))*4 + (d>>4))*2 + ((d>>3)&1))*256 + (t&31)*8 + (d&7)
// V:   frag idx = ((((h*64 + (t>>6))*2 + (d>>5))*4 + ((t>>4)&3))*2 + ((t>>3)&1))*256 + (d&31)*8 + (t&7)
__global__ void rope_reorg(const u16* __restrict__ qkv,
                           const float* __restrict__ sT, const float* __restrict__ cT,
                           u16* __restrict__ Qo, u16* __restrict__ Ko, u16* __restrict__ Vo)
{
  int idx = blockIdx.x * 256 + threadIdx.x;   // (t*16 + h)*32 + j
  int j = idx & 31;
  int h = (idx >> 5) & 15;
  int t = idx >> 9;
  const float QSC = 0.125f * 1.4426950408889634f;  // 1/sqrt(64) * log2(e)
  float s = sT[t * 32 + j], c = cT[t * 32 + j];
  const u16* row = qkv + (size_t)t * NQKV + h * HD;
  float q1 = bf2f(row[j]),        q2 = bf2f(row[j + 32]);
  float k1 = bf2f(row[DM + j]),   k2 = bf2f(row[DM + j + 32]);
  float qa = (q1 * c - q2 * s) * QSC, qb2 = (q2 * c + q1 * s) * QSC;
  float ka = k1 * c - k2 * s,         kb2 = k2 * c + k1 * s;

  size_t base = ((size_t)h * 128 + (t >> 5)) * 2048 + (size_t)(t & 31) * 8;
  size_t iA = base + (size_t)((j >> 4) * 2 + ((j >> 3) & 1)) * 256 + (j & 7);
  int j2 = j + 32;
  size_t iB = base + (size_t)((j2 >> 4) * 2 + ((j2 >> 3) & 1)) * 256 + (j2 & 7);
  Qo[iA] = f2bf(qa);  Qo[iB] = f2bf(qb2);
  Ko[iA] = f2bf(ka);  Ko[iB] = f2bf(kb2);

  u16 v1 = row[2 * DM + j], v2 = row[2 * DM + j + 32];
  size_t vb0 = ((size_t)h * 64 + (t >> 6)) * 4096 +
               (size_t)((t >> 4) & 3) * 512 + (size_t)((t >> 3) & 1) * 256 + (t & 7);
  Vo[vb0 + (size_t)(j & 31) * 8]        = v1;   // d = j   (<32): dt=0
  Vo[vb0 + 2048 + (size_t)(j & 31) * 8] = v2;   // d = j+32      : dt=1
}

// ---------------- causal flash attention (32x32 MFMA, reg-resident P) -------
// grid: 512 blocks, 256 thr. Block: q-tile of 128 rows, wave ws owns 32 rows.
// S^T = mfma(K,Q) (q = lane&31); O^T = mfma(V,P) shares that layout.
// K/V staged via global_load_lds into fragment-linear LDS (conflict-free),
// double-buffered, ONE barrier per kv-step. P via cvt_pk + permlane32_swap.
__global__ __launch_bounds__(256, 2) void fattn(const u16* __restrict__ Qf,
                                                const u16* __restrict__ Kf,
                                                const u16* __restrict__ Vf,
                                                u16* __restrict__ Oa)
{
  __shared__ __align__(16) u16 Ks[2][4096];
  __shared__ __align__(16) u16 Vs[2][4096];

  const int bid = blockIdx.x;
  const int h   = (bid & 7) * 2 + ((bid >> 3) & 1);  // 2 heads per XCD
  const int qb  = 31 - (bid >> 4);                   // big q-tiles first
  const int q0  = qb * 128;
  const int nkv = 2 * qb + 2;
  const int tid = threadIdx.x;
  const int ws  = tid >> 6;
  const int lane = tid & 63;
  const int l31 = lane & 31, hh = lane >> 5;
  const int q0s = q0 + ws * 32;
  const int qlane = q0s + l31;
  const int sb = ws * 512;                           // staging chunk (elems)

  const size_t hbase = (size_t)h * (TSEQ * HD);

  bf16x8 qf[4];
  {
    const u16* qp = Qf + hbase + (size_t)(q0s >> 5) * 2048;
#pragma unroll
    for (int kc = 0; kc < 4; ++kc)
      qf[kc] = *(const bf16x8*)(qp + kc * 512 + lane * 8);
  }

  f32x16 oacc0 = {}, oacc1 = {};
  float mrun = -3.0e38f, lrun = 0.f;

  // prologue: stage tile 0 -> buf 0
  {
    const u16* kg = Kf + hbase;
    const u16* vg = Vf + hbase;
    GLL16(kg + sb + lane * 8,        &Ks[0][sb]);
    GLL16(kg + 2048 + sb + lane * 8, &Ks[0][2048 + sb]);
    GLL16(vg + sb + lane * 8,        &Vs[0][sb]);
    GLL16(vg + 2048 + sb + lane * 8, &Vs[0][2048 + sb]);
  }
  asm volatile("s_waitcnt vmcnt(0)" ::: "memory");
  __syncthreads();

  for (int kt = 0; kt < nkv; ++kt) {
    const int cur = kt & 1;
    // issue next-tile staging (flies during compute)
    if (kt + 1 < nkv) {
      const u16* kg = Kf + hbase + (size_t)(kt + 1) * 4096;
      const u16* vg = Vf + hbase + (size_t)(kt + 1) * 4096;
      u16* kd = Ks[cur ^ 1];
      u16* vd = Vs[cur ^ 1];
      GLL16(kg + sb + lane * 8,        kd + sb);
      GLL16(kg + 2048 + sb + lane * 8, kd + 2048 + sb);
      GLL16(vg + sb + lane * 8,        vd + sb);
      GLL16(vg + 2048 + sb + lane * 8, vd + 2048 + sb);
    }
    const int kv0 = kt * 64;
    if (kv0 <= q0s + 31) {                 // wave has unmasked work in this tile
      // ---- QK^T: s0 = S^T[kv0..kv0+31][q], s1 = [+32..+63]
      f32x16 s0, s1;
      const u16* kb = Ks[cur];
      __builtin_amdgcn_s_setprio(1);
      {
        bf16x8 a0 = *(const bf16x8*)(kb + 0 * 512 + lane * 8);
        bf16x8 a1 = *(const bf16x8*)(kb + 4 * 512 + lane * 8);
        f32x16 z = {};
        s0 = __builtin_amdgcn_mfma_f32_32x32x16_bf16(a0, qf[0], z, 0, 0, 0);
        s1 = __builtin_amdgcn_mfma_f32_32x32x16_bf16(a1, qf[0], z, 0, 0, 0);
      }
#pragma unroll
      for (int kc = 1; kc < 4; ++kc) {
        bf16x8 a0 = *(const bf16x8*)(kb + (0 * 4 + kc) * 512 + lane * 8);
        bf16x8 a1 = *(const bf16x8*)(kb + (1 * 4 + kc) * 512 + lane * 8);
        s0 = __builtin_amdgcn_mfma_f32_32x32x16_bf16(a0, qf[kc], s0, 0, 0, 0);
        s1 = __builtin_amdgcn_mfma_f32_32x32x16_bf16(a1, qf[kc], s1, 0, 0, 0);
      }
      __builtin_amdgcn_s_setprio(0);

      // ---- causal mask (partial tiles only)
      if (kv0 + 63 > q0s) {
#pragma unroll
        for (int r = 0; r < 16; ++r) {
          int kvr = kv0 + (r & 3) + 8 * (r >> 2) + 4 * hh;
          if (kvr > qlane)      s0[r] = -3.0e38f;
          if (kvr + 32 > qlane) s1[r] = -3.0e38f;
        }
      }

      // ---- row max (in-lane tree + 1 shuffle)
      float tm = -3.0e38f;
#pragma unroll
      for (int r = 0; r < 16; ++r) tm = fmaxf(fmaxf(tm, s0[r]), s1[r]);
      tm = fmaxf(tm, __shfl_xor(tm, 32));

      // ---- defer-max (T13, log2 domain THR=8)
      if (!__all(tm <= mrun + 8.0f)) {
        float nm = fmaxf(mrun, tm);
        float sf = exp2f(mrun - nm);
        lrun *= sf;
        oacc0 *= sf;
        oacc1 *= sf;
        mrun = nm;
      }

      // ---- exp (in place) + row sum
      float rs = 0.f;
#pragma unroll
      for (int r = 0; r < 16; ++r) {
        s0[r] = exp2f(s0[r] - mrun);
        s1[r] = exp2f(s1[r] - mrun);
        rs += s0[r] + s1[r];
      }
      rs += __shfl_xor(rs, 32);
      lrun += rs;

      // ---- P fragments in-register: cvt_pk pairs + permlane32_swap
      bf16x8 pf[4];
#pragma unroll
      for (int kc = 0; kc < 4; ++kc) {
        const int e = 8 * (kc & 1);
        u32 Xa, Xb, Ya, Yb;
        if (kc < 2) {
          Xa = cvt_pk_bf16(s0[e + 0], s0[e + 1]);
          Xb = cvt_pk_bf16(s0[e + 2], s0[e + 3]);
          Ya = cvt_pk_bf16(s0[e + 4], s0[e + 5]);
          Yb = cvt_pk_bf16(s0[e + 6], s0[e + 7]);
        } else {
          Xa = cvt_pk_bf16(s1[e + 0], s1[e + 1]);
          Xb = cvt_pk_bf16(s1[e + 2], s1[e + 3]);
          Ya = cvt_pk_bf16(s1[e + 4], s1[e + 5]);
          Yb = cvt_pk_bf16(s1[e + 6], s1[e + 7]);
        }
        asm volatile("v_permlane32_swap_b32 %0, %1" : "+v"(Xa), "+v"(Ya));
        asm volatile("v_permlane32_swap_b32 %0, %1" : "+v"(Xb), "+v"(Yb));
        union { u32 u[4]; bf16x8 v; } pu;
        pu.u[0] = Xa; pu.u[1] = Xb; pu.u[2] = Ya; pu.u[3] = Yb;
        pf[kc] = pu.v;
      }

      // ---- PV: O^T += V * P
      const u16* vb = Vs[cur];
      __builtin_amdgcn_s_setprio(1);
#pragma unroll
      for (int kc = 0; kc < 4; ++kc) {
        bf16x8 v0 = *(const bf16x8*)(vb + (0 * 4 + kc) * 512 + lane * 8);
        bf16x8 v1 = *(const bf16x8*)(vb + (1 * 4 + kc) * 512 + lane * 8);
        oacc0 = __builtin_amdgcn_mfma_f32_32x32x16_bf16(v0, pf[kc], oacc0, 0, 0, 0);
        oacc1 = __builtin_amdgcn_mfma_f32_32x32x16_bf16(v1, pf[kc], oacc1, 0, 0, 0);
      }
      __builtin_amdgcn_s_setprio(0);
    }
    asm volatile("s_waitcnt vmcnt(0)" ::: "memory");
    __syncthreads();
  }

  // ---- epilogue: normalize (state is lane-local), transpose via LDS bounce
  {
    float inv = 1.f / lrun;
    u16* scr = &Ks[0][0] + ws * 2048;     // 4 KB per wave, reuses K dbuf
#pragma unroll
    for (int dt = 0; dt < 2; ++dt)
#pragma unroll
      for (int rq = 0; rq < 4; ++rq) {
        float v0 = (dt ? oacc1[4 * rq + 0] : oacc0[4 * rq + 0]) * inv;
        float v1 = (dt ? oacc1[4 * rq + 1] : oacc0[4 * rq + 1]) * inv;
        float v2 = (dt ? oacc1[4 * rq + 2] : oacc0[4 * rq + 2]) * inv;
        float v3 = (dt ? oacc1[4 * rq + 3] : oacc0[4 * rq + 3]) * inv;
        uint2 wv;
        wv.x = cvt_pk_bf16(v0, v1);
        wv.y = cvt_pk_bf16(v2, v3);
        int g = 4 * dt + rq;
        *(uint2*)(scr + l31 * 64 + ((g ^ (l31 & 7)) * 8) + 4 * hh) = wv;
      }
    // wave-private: compiler orders the dependent reads below
    const int q  = lane >> 1;
    const int dh = lane & 1;
#pragma unroll
    for (int c2 = 0; c2 < 4; ++c2) {
      int g2 = dh * 4 + c2;
      i32x4 v = *(const i32x4*)(scr + q * 64 + ((g2 ^ (q & 7)) * 8));
      *(i32x4*)(Oa + (size_t)(q0s + q) * DM + h * HD + dh * 32 + c2 * 8) = v;
    }
  }
}

extern "C" void kernel_launch(void* const* d_in, const int* in_sizes, int n_in,
                              void* d_out, int out_size, void* d_ws, size_t ws_size,
                              hipStream_t stream)
{
  const float* x     = (const float*)d_in[0];
  const float* wqkv  = (const float*)d_in[1];
  const float* wproj = (const float*)d_in[2];
  float* out = (float*)d_out;

  char* ws = (char*)d_ws;
  size_t off = 0;
  u16* xb   = (u16*)(ws + off); off += (size_t)TSEQ * DM * 2;
  u16* wqb  = (u16*)(ws + off); off += (size_t)NQKV * DM * 2;
  u16* wpb  = (u16*)(ws + off); off += (size_t)DM * DM * 2;
  u16* qkvb = (u16*)(ws + off); off += (size_t)TSEQ * NQKV * 2;
  u16* Qb   = (u16*)(ws + off); off += (size_t)NH * TSEQ * HD * 2;
  u16* Kb   = (u16*)(ws + off); off += (size_t)NH * TSEQ * HD * 2;
  u16* Vb   = (u16*)(ws + off); off += (size_t)NH * TSEQ * HD * 2;
  u16* Ob   = (u16*)(ws + off); off += (size_t)TSEQ * DM * 2;
  float* sT = (float*)(ws + off); off += (size_t)TSEQ * 32 * 4;
  float* cT = (float*)(ws + off); off += (size_t)TSEQ * 32 * 4;

  cast_kernel<<<(TSEQ * DM / 4) / 256, 256, 0, stream>>>(x, xb, TSEQ * DM / 4);
  cast_kernel<<<(NQKV * DM / 4) / 256, 256, 0, stream>>>(wqkv, wqb, NQKV * DM / 4);
  cast_kernel<<<(DM * DM / 4) / 256, 256, 0, stream>>>(wproj, wpb, DM * DM / 4);
  rope_table<<<(TSEQ * 32) / 256, 256, 0, stream>>>(sT, cT);

  gemm_bt<1><<<dim3(NQKV / 128, TSEQ / 128), 256, 0, stream>>>(xb, wqb, qkvb, TSEQ, NQKV, DM);

  rope_reorg<<<(TSEQ * NH * 32) / 256, 256, 0, stream>>>(qkvb, sT, cT, Qb, Kb, Vb);

  fattn<<<NH * 32, 256, 0, stream>>>(Qb, Kb, Vb, Ob);

  gemm_bt<0><<<dim3(DM / 128, TSEQ / 128), 256, 0, stream>>>(Ob, wpb, out, TSEQ, DM, DM);
}

// Round 5
// 194.662 us; speedup vs baseline: 1.0543x; 1.0543x over previous
//
#include <hip/hip_runtime.h>
#include <hip/hip_bf16.h>
#include <stdint.h>

#define TSEQ 4096
#define DM   1024
#define NH   16
#define HD   64
#define NQKV 3072

typedef unsigned short u16;
typedef unsigned int   u32;
typedef __attribute__((ext_vector_type(8)))  short bf16x8;
typedef __attribute__((ext_vector_type(4)))  float f32x4;
typedef __attribute__((ext_vector_type(16))) float f32x16;
typedef __attribute__((ext_vector_type(4)))  int   i32x4;

static __device__ __forceinline__ u16 f2bf(float f) {
  u32 u = __float_as_uint(f);
  u32 r = (u + 0x7FFFu + ((u >> 16) & 1u)) >> 16;   // RNE
  return (u16)r;
}
static __device__ __forceinline__ float bf2f(u16 u) {
  return __uint_as_float(((u32)u) << 16);
}
static __device__ __forceinline__ u32 cvt_pk_bf16(float lo, float hi) {
  u32 r;
  asm("v_cvt_pk_bf16_f32 %0, %1, %2" : "=v"(r) : "v"(lo), "v"(hi));
  return r;
}

#define GLL16(g, l) __builtin_amdgcn_global_load_lds( \
    (const __attribute__((address_space(1))) u32*)(g), \
    (__attribute__((address_space(3))) u32*)(l), 16, 0, 0)

// ---------------- cast fp32 -> bf16 (4 elems/thread) ----------------
__global__ void cast_kernel(const float* __restrict__ in, u16* __restrict__ out, int n4) {
  int i = blockIdx.x * 256 + threadIdx.x;
  if (i >= n4) return;
  float4 v = ((const float4*)in)[i];
  ushort4 o;
  o.x = f2bf(v.x); o.y = f2bf(v.y); o.z = f2bf(v.z); o.w = f2bf(v.w);
  ((ushort4*)out)[i] = o;
}

// ---------------- RoPE sin/cos table [T][32] ----------------
__global__ void rope_table(float* __restrict__ sT, float* __restrict__ cT) {
  int i = blockIdx.x * 256 + threadIdx.x;   // t*32 + j
  int t = i >> 5, j = i & 31;
  float inv = exp2f((float)j * (-13.287712379549449f / 32.0f)); // 10000^(-j/32)
  float ang = (float)t * inv;
  sT[i] = sinf(ang);
  cT[i] = cosf(ang);
}

// ---------------- GEMM C[M,N] = A[M,K] * B[N,K]^T (bf16 in, fp32 acc) --------
template<int WRITE_BF16>
__global__ __launch_bounds__(256) void gemm_bt(const u16* __restrict__ A,
                                               const u16* __restrict__ B,
                                               void* __restrict__ Cout,
                                               int M, int N, int K)
{
  __shared__ __align__(16) u16 As[128 * 32];
  __shared__ __align__(16) u16 Bs[128 * 32];
  const int tid  = threadIdx.x;
  const int wave = tid >> 6, lane = tid & 63;
  const int l15  = lane & 15, lh = lane >> 4;
  const int wr   = wave >> 1, wc = wave & 1;

  const int nwg = gridDim.x * gridDim.y;
  int lin = blockIdx.y * gridDim.x + blockIdx.x;
  lin = (lin & 7) * (nwg >> 3) + (lin >> 3);          // nwg % 8 == 0
  const size_t bm = (size_t)(lin / gridDim.x);
  const size_t bn = (size_t)(lin % gridDim.x);

  f32x4 acc[4][4] = {};

  const u16* Ab = A + bm * 128 * (size_t)K;
  const u16* Bb = B + bn * 128 * (size_t)K;

  for (int k0 = 0; k0 < K; k0 += 32) {
    __syncthreads();
#pragma unroll
    for (int j = 0; j < 2; ++j) {
      const int ch = j * 4 + wave;            // 8 chunks of 1024B per tile
      const int e  = ch * 512 + lane * 8;     // element within tile (row-major [128][32])
      const int r  = e >> 5, c = e & 31;
      GLL16(Ab + (size_t)r * K + k0 + c, As + ch * 512);
      GLL16(Bb + (size_t)r * K + k0 + c, Bs + ch * 512);
    }
    asm volatile("s_waitcnt vmcnt(0)" ::: "memory");
    __syncthreads();

    bf16x8 af[4], bfr[4];
#pragma unroll
    for (int m = 0; m < 4; ++m)
      af[m] = *(const bf16x8*)(As + (wr * 64 + m * 16 + l15) * 32 + lh * 8);
#pragma unroll
    for (int n = 0; n < 4; ++n)
      bfr[n] = *(const bf16x8*)(Bs + (wc * 64 + n * 16 + l15) * 32 + lh * 8);
#pragma unroll
    for (int m = 0; m < 4; ++m)
#pragma unroll
      for (int n = 0; n < 4; ++n)
        acc[m][n] = __builtin_amdgcn_mfma_f32_16x16x32_bf16(af[m], bfr[n], acc[m][n], 0, 0, 0);
  }

#pragma unroll
  for (int m = 0; m < 4; ++m)
#pragma unroll
    for (int n = 0; n < 4; ++n)
#pragma unroll
      for (int r = 0; r < 4; ++r) {
        size_t row = bm * 128 + wr * 64 + m * 16 + lh * 4 + r;
        size_t col = bn * 128 + wc * 64 + n * 16 + l15;
        float v = acc[m][n][r];
        if (WRITE_BF16) ((u16*)Cout)[row * N + col] = f2bf(v);
        else            ((float*)Cout)[row * N + col] = v;
      }
}

// ---------------- RoPE + head-split into MFMA-fragment-tiled layouts --------
// Q/K: frag idx = (((h*128 + (t>>5))*4 + (d>>4))*2 + ((d>>3)&1))*256 + (t&31)*8 + (d&7)
// V:   frag idx = ((((h*64 + (t>>6))*2 + (d>>5))*4 + ((t>>4)&3))*2 + ((t>>3)&1))*256 + (d&31)*8 + (t&7)
__global__ void rope_reorg(const u16* __restrict__ qkv,
                           const float* __restrict__ sT, const float* __restrict__ cT,
                           u16* __restrict__ Qo, u16* __restrict__ Ko, u16* __restrict__ Vo)
{
  int idx = blockIdx.x * 256 + threadIdx.x;   // (t*16 + h)*32 + j
  int j = idx & 31;
  int h = (idx >> 5) & 15;
  int t = idx >> 9;
  const float QSC = 0.125f * 1.4426950408889634f;  // 1/sqrt(64) * log2(e)
  float s = sT[t * 32 + j], c = cT[t * 32 + j];
  const u16* row = qkv + (size_t)t * NQKV + h * HD;
  float q1 = bf2f(row[j]),        q2 = bf2f(row[j + 32]);
  float k1 = bf2f(row[DM + j]),   k2 = bf2f(row[DM + j + 32]);
  float qa = (q1 * c - q2 * s) * QSC, qb2 = (q2 * c + q1 * s) * QSC;
  float ka = k1 * c - k2 * s,         kb2 = k2 * c + k1 * s;

  size_t base = ((size_t)h * 128 + (t >> 5)) * 2048 + (size_t)(t & 31) * 8;
  size_t iA = base + (size_t)((j >> 4) * 2 + ((j >> 3) & 1)) * 256 + (j & 7);
  int j2 = j + 32;
  size_t iB = base + (size_t)((j2 >> 4) * 2 + ((j2 >> 3) & 1)) * 256 + (j2 & 7);
  Qo[iA] = f2bf(qa);  Qo[iB] = f2bf(qb2);
  Ko[iA] = f2bf(ka);  Ko[iB] = f2bf(kb2);

  u16 v1 = row[2 * DM + j], v2 = row[2 * DM + j + 32];
  size_t vb0 = ((size_t)h * 64 + (t >> 6)) * 4096 +
               (size_t)((t >> 4) & 3) * 512 + (size_t)((t >> 3) & 1) * 256 + (t & 7);
  Vo[vb0 + (size_t)(j & 31) * 8]        = v1;   // d = j   (<32): dt=0
  Vo[vb0 + 2048 + (size_t)(j & 31) * 8] = v2;   // d = j+32      : dt=1
}

// ---------------- causal flash attention: 1 wave per block, no barriers -----
// grid: 2048 blocks x 64 thr. Wave = 32 q rows (qt = 127-(bid>>4), big first).
// K/V read DIRECTLY global(L2)->reg as MFMA A-fragments (fragment-tiled layout).
// K ping-pong double-buffered across steps; V loaded at step start, used in PV.
// S^T = mfma(K,Q) (q = lane&31); O^T = mfma(V,P); P in-reg via cvt_pk+permlane.
#define ATTN_STEP(KARR, ktv)                                                     \
  do {                                                                           \
    const int kv0 = (ktv) * 64;                                                  \
    f32x16 s0, s1;                                                               \
    __builtin_amdgcn_s_setprio(1);                                               \
    {                                                                            \
      f32x16 z = {};                                                             \
      s0 = __builtin_amdgcn_mfma_f32_32x32x16_bf16(KARR[0], qf[0], z, 0, 0, 0);  \
      s1 = __builtin_amdgcn_mfma_f32_32x32x16_bf16(KARR[4], qf[0], z, 0, 0, 0);  \
    }                                                                            \
    _Pragma("unroll")                                                            \
    for (int kc = 1; kc < 4; ++kc) {                                             \
      s0 = __builtin_amdgcn_mfma_f32_32x32x16_bf16(KARR[kc], qf[kc], s0, 0, 0, 0);\
      s1 = __builtin_amdgcn_mfma_f32_32x32x16_bf16(KARR[4 + kc], qf[kc], s1, 0, 0, 0);\
    }                                                                            \
    __builtin_amdgcn_s_setprio(0);                                               \
    if (kv0 + 63 > q0s) {                                                        \
      _Pragma("unroll")                                                          \
      for (int r = 0; r < 16; ++r) {                                             \
        int kvr = kv0 + (r & 3) + 8 * (r >> 2) + 4 * hh;                         \
        if (kvr > qlane)      s0[r] = -3.0e38f;                                  \
        if (kvr + 32 > qlane) s1[r] = -3.0e38f;                                  \
      }                                                                          \
    }                                                                            \
    float tm = -3.0e38f;                                                         \
    _Pragma("unroll")                                                            \
    for (int r = 0; r < 16; ++r) tm = fmaxf(fmaxf(tm, s0[r]), s1[r]);            \
    tm = fmaxf(tm, __shfl_xor(tm, 32));                                          \
    if (!__all(tm <= mrun + 8.0f)) {                                             \
      float nm = fmaxf(mrun, tm);                                                \
      float sf = exp2f(mrun - nm);                                               \
      lrun *= sf;                                                                \
      oacc0 *= sf;                                                               \
      oacc1 *= sf;                                                               \
      mrun = nm;                                                                 \
    }                                                                            \
    float rs = 0.f;                                                              \
    _Pragma("unroll")                                                            \
    for (int r = 0; r < 16; ++r) {                                               \
      s0[r] = exp2f(s0[r] - mrun);                                               \
      s1[r] = exp2f(s1[r] - mrun);                                               \
      rs += s0[r] + s1[r];                                                       \
    }                                                                            \
    rs += __shfl_xor(rs, 32);                                                    \
    lrun += rs;                                                                  \
    bf16x8 pf[4];                                                                \
    _Pragma("unroll")                                                            \
    for (int kc = 0; kc < 4; ++kc) {                                             \
      const int e = 8 * (kc & 1);                                                \
      u32 Xa, Xb, Ya, Yb;                                                        \
      if (kc < 2) {                                                              \
        Xa = cvt_pk_bf16(s0[e + 0], s0[e + 1]);                                  \
        Xb = cvt_pk_bf16(s0[e + 2], s0[e + 3]);                                  \
        Ya = cvt_pk_bf16(s0[e + 4], s0[e + 5]);                                  \
        Yb = cvt_pk_bf16(s0[e + 6], s0[e + 7]);                                  \
      } else {                                                                   \
        Xa = cvt_pk_bf16(s1[e + 0], s1[e + 1]);                                  \
        Xb = cvt_pk_bf16(s1[e + 2], s1[e + 3]);                                  \
        Ya = cvt_pk_bf16(s1[e + 4], s1[e + 5]);                                  \
        Yb = cvt_pk_bf16(s1[e + 6], s1[e + 7]);                                  \
      }                                                                          \
      asm volatile("v_permlane32_swap_b32 %0, %1" : "+v"(Xa), "+v"(Ya));         \
      asm volatile("v_permlane32_swap_b32 %0, %1" : "+v"(Xb), "+v"(Yb));         \
      union { u32 u[4]; bf16x8 v; } pu;                                          \
      pu.u[0] = Xa; pu.u[1] = Xb; pu.u[2] = Ya; pu.u[3] = Yb;                    \
      pf[kc] = pu.v;                                                             \
    }                                                                            \
    __builtin_amdgcn_s_setprio(1);                                               \
    _Pragma("unroll")                                                            \
    for (int kc = 0; kc < 4; ++kc) {                                             \
      oacc0 = __builtin_amdgcn_mfma_f32_32x32x16_bf16(vv[kc], pf[kc], oacc0, 0, 0, 0);      \
      oacc1 = __builtin_amdgcn_mfma_f32_32x32x16_bf16(vv[4 + kc], pf[kc], oacc1, 0, 0, 0);  \
    }                                                                            \
    __builtin_amdgcn_s_setprio(0);                                               \
  } while (0)

__global__ __launch_bounds__(64) void fattn(const u16* __restrict__ Qf,
                                            const u16* __restrict__ Kf,
                                            const u16* __restrict__ Vf,
                                            u16* __restrict__ Oa)
{
  __shared__ __align__(16) u16 scr[2048];

  const int bid = blockIdx.x;
  const int h   = bid & 15;                 // h and h+8 share XCD (bid&7)
  const int qt  = 127 - (bid >> 4);         // big q-tiles dispatched first
  const int q0s = qt * 32;
  const int lane = threadIdx.x;
  const int l31 = lane & 31, hh = lane >> 5;
  const int qlane = q0s + l31;
  const int nkv = (q0s >> 6) + 1;

  const size_t hbase = (size_t)h * (TSEQ * HD);
  const u16* kg = Kf + hbase;
  const u16* vg = Vf + hbase;

  bf16x8 qf[4];
  {
    const u16* qp = Qf + hbase + (size_t)(q0s >> 5) * 2048;
#pragma unroll
    for (int kc = 0; kc < 4; ++kc)
      qf[kc] = *(const bf16x8*)(qp + kc * 512 + lane * 8);
  }

  f32x16 oacc0 = {}, oacc1 = {};
  float mrun = -3.0e38f, lrun = 0.f;

  bf16x8 kA[8], kB[8];
#pragma unroll
  for (int i = 0; i < 8; ++i)
    kA[i] = *(const bf16x8*)(kg + i * 512 + lane * 8);

  int kt = 0;
  for (;;) {
    {   // step uses kA, prefetches into kB
      bf16x8 vv[8];
      const u16* vt = vg + (size_t)kt * 4096;
#pragma unroll
      for (int i = 0; i < 8; ++i)
        vv[i] = *(const bf16x8*)(vt + i * 512 + lane * 8);
      if (kt + 1 < nkv) {
        const u16* kn = kg + (size_t)(kt + 1) * 4096;
#pragma unroll
        for (int i = 0; i < 8; ++i)
          kB[i] = *(const bf16x8*)(kn + i * 512 + lane * 8);
      }
      ATTN_STEP(kA, kt);
    }
    if (++kt == nkv) break;
    {   // step uses kB, prefetches into kA
      bf16x8 vv[8];
      const u16* vt = vg + (size_t)kt * 4096;
#pragma unroll
      for (int i = 0; i < 8; ++i)
        vv[i] = *(const bf16x8*)(vt + i * 512 + lane * 8);
      if (kt + 1 < nkv) {
        const u16* kn = kg + (size_t)(kt + 1) * 4096;
#pragma unroll
        for (int i = 0; i < 8; ++i)
          kA[i] = *(const bf16x8*)(kn + i * 512 + lane * 8);
      }
      ATTN_STEP(kB, kt);
    }
    if (++kt == nkv) break;
  }

  // ---- epilogue: normalize (state lane-local), transpose via LDS bounce ----
  {
    float inv = 1.f / lrun;
#pragma unroll
    for (int dt = 0; dt < 2; ++dt)
#pragma unroll
      for (int rq = 0; rq < 4; ++rq) {
        float v0 = (dt ? oacc1[4 * rq + 0] : oacc0[4 * rq + 0]) * inv;
        float v1 = (dt ? oacc1[4 * rq + 1] : oacc0[4 * rq + 1]) * inv;
        float v2 = (dt ? oacc1[4 * rq + 2] : oacc0[4 * rq + 2]) * inv;
        float v3 = (dt ? oacc1[4 * rq + 3] : oacc0[4 * rq + 3]) * inv;
        uint2 wv;
        wv.x = cvt_pk_bf16(v0, v1);
        wv.y = cvt_pk_bf16(v2, v3);
        int g = 4 * dt + rq;
        *(uint2*)(scr + l31 * 64 + ((g ^ (l31 & 7)) * 8) + 4 * hh) = wv;
      }
    asm volatile("s_waitcnt lgkmcnt(0)" ::: "memory");
    __builtin_amdgcn_sched_barrier(0);
    const int q  = lane >> 1;
    const int dh = lane & 1;
#pragma unroll
    for (int c2 = 0; c2 < 4; ++c2) {
      int g2 = dh * 4 + c2;
      i32x4 v = *(const i32x4*)(scr + q * 64 + ((g2 ^ (q & 7)) * 8));
      *(i32x4*)(Oa + (size_t)(q0s + q) * DM + h * HD + dh * 32 + c2 * 8) = v;
    }
  }
}

extern "C" void kernel_launch(void* const* d_in, const int* in_sizes, int n_in,
                              void* d_out, int out_size, void* d_ws, size_t ws_size,
                              hipStream_t stream)
{
  const float* x     = (const float*)d_in[0];
  const float* wqkv  = (const float*)d_in[1];
  const float* wproj = (const float*)d_in[2];
  float* out = (float*)d_out;

  char* ws = (char*)d_ws;
  size_t off = 0;
  u16* xb   = (u16*)(ws + off); off += (size_t)TSEQ * DM * 2;
  u16* wqb  = (u16*)(ws + off); off += (size_t)NQKV * DM * 2;
  u16* wpb  = (u16*)(ws + off); off += (size_t)DM * DM * 2;
  u16* qkvb = (u16*)(ws + off); off += (size_t)TSEQ * NQKV * 2;
  u16* Qb   = (u16*)(ws + off); off += (size_t)NH * TSEQ * HD * 2;
  u16* Kb   = (u16*)(ws + off); off += (size_t)NH * TSEQ * HD * 2;
  u16* Vb   = (u16*)(ws + off); off += (size_t)NH * TSEQ * HD * 2;
  u16* Ob   = (u16*)(ws + off); off += (size_t)TSEQ * DM * 2;
  float* sT = (float*)(ws + off); off += (size_t)TSEQ * 32 * 4;
  float* cT = (float*)(ws + off); off += (size_t)TSEQ * 32 * 4;

  cast_kernel<<<(TSEQ * DM / 4) / 256, 256, 0, stream>>>(x, xb, TSEQ * DM / 4);
  cast_kernel<<<(NQKV * DM / 4) / 256, 256, 0, stream>>>(wqkv, wqb, NQKV * DM / 4);
  cast_kernel<<<(DM * DM / 4) / 256, 256, 0, stream>>>(wproj, wpb, DM * DM / 4);
  rope_table<<<(TSEQ * 32) / 256, 256, 0, stream>>>(sT, cT);

  gemm_bt<1><<<dim3(NQKV / 128, TSEQ / 128), 256, 0, stream>>>(xb, wqb, qkvb, TSEQ, NQKV, DM);

  rope_reorg<<<(TSEQ * NH * 32) / 256, 256, 0, stream>>>(qkvb, sT, cT, Qb, Kb, Vb);

  fattn<<<NH * 128, 64, 0, stream>>>(Qb, Kb, Vb, Ob);

  gemm_bt<0><<<dim3(DM / 128, TSEQ / 128), 256, 0, stream>>>(Ob, wpb, out, TSEQ, DM, DM);
}

// Round 7
// 179.733 us; speedup vs baseline: 1.1419x; 1.0831x over previous
//
#include <hip/hip_runtime.h>
#include <hip/hip_bf16.h>
#include <stdint.h>

#define TSEQ 4096
#define DM   1024
#define NH   16
#define HD   64
#define NQKV 3072

typedef unsigned short u16;
typedef unsigned int   u32;
typedef __attribute__((ext_vector_type(8)))  short bf16x8;
typedef __attribute__((ext_vector_type(4)))  float f32x4;
typedef __attribute__((ext_vector_type(4)))  int   i32x4;

static __device__ __forceinline__ u16 f2bf(float f) {
  u32 u = __float_as_uint(f);
  u32 r = (u + 0x7FFFu + ((u >> 16) & 1u)) >> 16;   // RNE
  return (u16)r;
}
static __device__ __forceinline__ float bf2f(u16 u) {
  return __uint_as_float(((u32)u) << 16);
}
static __device__ __forceinline__ u32 cvt_pk_bf16(float lo, float hi) {
  u32 r;
  asm("v_cvt_pk_bf16_f32 %0, %1, %2" : "=v"(r) : "v"(lo), "v"(hi));
  return r;
}
static __device__ __forceinline__ float fexp2(float x) {   // guaranteed v_exp_f32
  float r;
  asm("v_exp_f32 %0, %1" : "=v"(r) : "v"(x));
  return r;
}

#define GLL16(g, l) __builtin_amdgcn_global_load_lds( \
    (const __attribute__((address_space(1))) u32*)(g), \
    (__attribute__((address_space(3))) u32*)(l), 16, 0, 0)

// ---------------- fused cast fp32 -> bf16 for x, W_qkv, W_proj --------------
#define N4X  (TSEQ * DM / 4)
#define N4Q  (NQKV * DM / 4)
#define N4P  (DM * DM / 4)
__global__ void cast3_kernel(const float* __restrict__ x, u16* __restrict__ xo,
                             const float* __restrict__ wq, u16* __restrict__ wqo,
                             const float* __restrict__ wp, u16* __restrict__ wpo) {
  int i = blockIdx.x * 256 + threadIdx.x;
  const float* in; u16* out; int k;
  if (i < N4X)            { in = x;  out = xo;  k = i; }
  else if (i < N4X + N4Q) { in = wq; out = wqo; k = i - N4X; }
  else if (i < N4X + N4Q + N4P) { in = wp; out = wpo; k = i - N4X - N4Q; }
  else return;
  float4 v = ((const float4*)in)[k];
  ushort4 o;
  o.x = f2bf(v.x); o.y = f2bf(v.y); o.z = f2bf(v.z); o.w = f2bf(v.w);
  ((ushort4*)out)[k] = o;
}

// ---------------- RoPE sin/cos table [T][32] ----------------
__global__ void rope_table(float* __restrict__ sT, float* __restrict__ cT) {
  int i = blockIdx.x * 256 + threadIdx.x;   // t*32 + j
  int t = i >> 5, j = i & 31;
  float inv = exp2f((float)j * (-13.287712379549449f / 32.0f)); // 10000^(-j/32)
  float ang = (float)t * inv;
  sT[i] = sinf(ang);
  cT[i] = cosf(ang);
}

// ---------------- GEMM C[M,N] = A[M,K] * B[N,K]^T (bf16 in, fp32 acc) --------
template<int WRITE_BF16>
__global__ __launch_bounds__(256) void gemm_bt(const u16* __restrict__ A,
                                               const u16* __restrict__ B,
                                               void* __restrict__ Cout,
                                               int M, int N, int K)
{
  __shared__ __align__(16) u16 As[128 * 32];
  __shared__ __align__(16) u16 Bs[128 * 32];
  const int tid  = threadIdx.x;
  const int wave = tid >> 6, lane = tid & 63;
  const int l15  = lane & 15, lh = lane >> 4;
  const int wr   = wave >> 1, wc = wave & 1;

  const int nwg = gridDim.x * gridDim.y;
  int lin = blockIdx.y * gridDim.x + blockIdx.x;
  lin = (lin & 7) * (nwg >> 3) + (lin >> 3);          // nwg % 8 == 0
  const size_t bm = (size_t)(lin / gridDim.x);
  const size_t bn = (size_t)(lin % gridDim.x);

  f32x4 acc[4][4] = {};

  const u16* Ab = A + bm * 128 * (size_t)K;
  const u16* Bb = B + bn * 128 * (size_t)K;

  for (int k0 = 0; k0 < K; k0 += 32) {
    __syncthreads();
#pragma unroll
    for (int j = 0; j < 2; ++j) {
      const int ch = j * 4 + wave;            // 8 chunks of 1024B per tile
      const int e  = ch * 512 + lane * 8;     // element within tile (row-major [128][32])
      const int r  = e >> 5, c = e & 31;
      GLL16(Ab + (size_t)r * K + k0 + c, As + ch * 512);
      GLL16(Bb + (size_t)r * K + k0 + c, Bs + ch * 512);
    }
    asm volatile("s_waitcnt vmcnt(0)" ::: "memory");
    __syncthreads();

    bf16x8 af[4], bfr[4];
#pragma unroll
    for (int m = 0; m < 4; ++m)
      af[m] = *(const bf16x8*)(As + (wr * 64 + m * 16 + l15) * 32 + lh * 8);
#pragma unroll
    for (int n = 0; n < 4; ++n)
      bfr[n] = *(const bf16x8*)(Bs + (wc * 64 + n * 16 + l15) * 32 + lh * 8);
#pragma unroll
    for (int m = 0; m < 4; ++m)
#pragma unroll
      for (int n = 0; n < 4; ++n)
        acc[m][n] = __builtin_amdgcn_mfma_f32_16x16x32_bf16(af[m], bfr[n], acc[m][n], 0, 0, 0);
  }

#pragma unroll
  for (int m = 0; m < 4; ++m)
#pragma unroll
    for (int n = 0; n < 4; ++n)
#pragma unroll
      for (int r = 0; r < 4; ++r) {
        size_t row = bm * 128 + wr * 64 + m * 16 + lh * 4 + r;
        size_t col = bn * 128 + wc * 64 + n * 16 + l15;
        float v = acc[m][n][r];
        if (WRITE_BF16) ((u16*)Cout)[row * N + col] = f2bf(v);
        else            ((float*)Cout)[row * N + col] = v;
      }
}

// ---------------- RoPE + head-split into 16x16-MFMA-fragment layouts --------
// Q,K (B/A-frag, 16 t-rows x 32 d): idx = (((h*256+(t>>4))*2+(d>>5))*64 + (t&15)+((d>>3)&3)*16)*8 + (d&7)
// V^T (A-frag, 16 d-rows x 32 kv):  idx = ((((h*64+(t>>6))*4+(d>>4))*2+((t>>5)&1))*64 + (d&15)+((t>>3)&3)*16)*8 + (t&7)
__global__ void rope_reorg(const u16* __restrict__ qkv,
                           const float* __restrict__ sT, const float* __restrict__ cT,
                           u16* __restrict__ Qo, u16* __restrict__ Ko, u16* __restrict__ Vo)
{
  int idx = blockIdx.x * 256 + threadIdx.x;   // (t*16 + h)*32 + j
  int j = idx & 31;
  int h = (idx >> 5) & 15;
  int t = idx >> 9;
  const float QSC = 0.125f * 1.4426950408889634f;  // 1/sqrt(64) * log2(e)
  float s = sT[t * 32 + j], c = cT[t * 32 + j];
  const u16* row = qkv + (size_t)t * NQKV + h * HD;
  float q1 = bf2f(row[j]),        q2 = bf2f(row[j + 32]);
  float k1 = bf2f(row[DM + j]),   k2 = bf2f(row[DM + j + 32]);
  float qa = (q1 * c - q2 * s) * QSC, qb2 = (q2 * c + q1 * s) * QSC;
  float ka = k1 * c - k2 * s,         kb2 = k2 * c + k1 * s;

  int d0 = j, d1 = j + 32;
  size_t qk0 = ((((size_t)h * 256 + (t >> 4)) * 2 + (d0 >> 5)) * 64 +
                (t & 15) + ((d0 >> 3) & 3) * 16) * 8 + (d0 & 7);
  size_t qk1 = ((((size_t)h * 256 + (t >> 4)) * 2 + (d1 >> 5)) * 64 +
                (t & 15) + ((d1 >> 3) & 3) * 16) * 8 + (d1 & 7);
  Qo[qk0] = f2bf(qa);  Qo[qk1] = f2bf(qb2);
  Ko[qk0] = f2bf(ka);  Ko[qk1] = f2bf(kb2);

  size_t vt = (size_t)((t >> 5) & 1) * 64 + ((t >> 3) & 3) * 16;  // kv-chunk+colgrp part
  size_t vbase = (((size_t)h * 64 + (t >> 6)) * 8) * 64;          // 8 blocks per kv-tile
  size_t v0 = (vbase + (size_t)(d0 >> 4) * 128 + vt + (d0 & 15)) * 8 + (t & 7);
  size_t v1 = (vbase + (size_t)(d1 >> 4) * 128 + vt + (d1 & 15)) * 8 + (t & 7);
  Vo[v0] = row[2 * DM + j];
  Vo[v1] = row[2 * DM + j + 32];
}

// ---------------- causal flash attention ----------------
// grid 16 heads x 64 q-tiles (1024 blocks, big-first), 4 waves x 16 q-rows.
// S^T = mfma(K,Q): q = lane&15 in-lane softmax state. O^T = mfma(V,P): same layout.
// K/V: global_load_lds (fragment-linear, conflict-free), double-buffered, 1 barrier/step.
// Deferred max: exp with stale m; post-PV pmax<=256 check; tile 0 computes real max.
__global__ __launch_bounds__(256) void fattn(const u16* __restrict__ Qf,
                                             const u16* __restrict__ Kf,
                                             const u16* __restrict__ Vf,
                                             u16* __restrict__ Oa)
{
  __shared__ __align__(16) u16 Ks[2][4096];
  __shared__ __align__(16) u16 Vs[2][4096];
  __shared__ __align__(16) u16 Ps[4][1024];

  const int bid = blockIdx.x;
  const int h   = bid & (NH - 1);            // h, h+8 share XCD (bid&7)
  const int qt  = 63 - (bid >> 4);           // big q-tiles first
  const int q0  = qt * 64;
  const int nkv = qt + 1;
  const int tid = threadIdx.x;
  const int wave = tid >> 6, lane = tid & 63;
  const int l15 = lane & 15, lh = lane >> 4;
  const int qg  = wave * 16 + l15;           // local q row this lane owns
  const int lb  = lane * 8;                  // linear fragment read offset (elems)

  const size_t hbase = (size_t)h * (TSEQ * HD);
  const u16* kg = Kf + hbase;
  const u16* vg = Vf + hbase;

  // P store offsets (elems), per n-tile: frag-linear B layout
  u16* const pw = &Ps[wave][0];
  int pso[4];
#pragma unroll
  for (int n = 0; n < 4; ++n)
    pso[n] = (n >> 1) * 512 + (((2 * n + (lh >> 1)) & 3) * 16 + l15) * 8 + (lh & 1) * 4;

  // Q fragments (B-operand)
  bf16x8 qf0, qf1;
  {
    const u16* qp = Qf + hbase + (size_t)(q0 / 16 + wave) * 1024;
    qf0 = *(const bf16x8*)(qp + lb);
    qf1 = *(const bf16x8*)(qp + 512 + lb);
  }

  f32x4 oacc[4] = {};
  float mrun = 0.f, lrun = 0.f;

  // prologue: stage tile 0 -> buf 0
#pragma unroll
  for (int c = 0; c < 2; ++c) {
    GLL16(kg + tid * 8 + c * 2048, &Ks[0][tid * 8 + c * 2048]);
    GLL16(vg + tid * 8 + c * 2048, &Vs[0][tid * 8 + c * 2048]);
  }
  asm volatile("s_waitcnt vmcnt(0)" ::: "memory");
  __syncthreads();

  for (int kt = 0; kt < nkv; ++kt) {
    const int cur = kt & 1;
    // issue next-tile staging (flies during this step's compute)
    if (kt + 1 < nkv) {
      const u16* kg2 = kg + (size_t)(kt + 1) * 4096;
      const u16* vg2 = vg + (size_t)(kt + 1) * 4096;
#pragma unroll
      for (int c = 0; c < 2; ++c) {
        GLL16(kg2 + tid * 8 + c * 2048, &Ks[cur ^ 1][tid * 8 + c * 2048]);
        GLL16(vg2 + tid * 8 + c * 2048, &Vs[cur ^ 1][tid * 8 + c * 2048]);
      }
    }
    const u16* kb = Ks[cur];
    const u16* vb = Vs[cur];

    // ---- S^T = mfma(K, Q): sacc[n][r] = S[kv=n*16+lh*4+r][q=l15] (log2 domain)
    f32x4 sacc[4];
    __builtin_amdgcn_s_setprio(1);
#pragma unroll
    for (int n = 0; n < 4; ++n) {
      bf16x8 kf0 = *(const bf16x8*)(kb + (n * 2 + 0) * 512 + lb);
      bf16x8 kf1 = *(const bf16x8*)(kb + (n * 2 + 1) * 512 + lb);
      f32x4 z = {0.f, 0.f, 0.f, 0.f};
      sacc[n] = __builtin_amdgcn_mfma_f32_16x16x32_bf16(kf0, qf0, z, 0, 0, 0);
      sacc[n] = __builtin_amdgcn_mfma_f32_16x16x32_bf16(kf1, qf1, sacc[n], 0, 0, 0);
    }
    __builtin_amdgcn_s_setprio(0);

    if (kt == qt) {                          // diagonal tile: mask kv > q (local)
#pragma unroll
      for (int n = 0; n < 4; ++n)
#pragma unroll
        for (int r = 0; r < 4; ++r)
          if (n * 16 + lh * 4 + r > qg) sacc[n][r] = -3.0e38f;
    }

    if (kt == 0) {                           // first tile: real max before exp
      float tm = fmaxf(fmaxf(sacc[0][0], sacc[0][1]), fmaxf(sacc[0][2], sacc[0][3]));
#pragma unroll
      for (int n = 1; n < 4; ++n)
        tm = fmaxf(tm, fmaxf(fmaxf(sacc[n][0], sacc[n][1]), fmaxf(sacc[n][2], sacc[n][3])));
      tm = fmaxf(tm, __shfl_xor(tm, 16));
      tm = fmaxf(tm, __shfl_xor(tm, 32));
      mrun = tm;
    }

    // ---- exp with (possibly stale) mrun; track pmax off the critical path
    float rs = 0.f, pmax = 0.f;
#pragma unroll
    for (int n = 0; n < 4; ++n) {
      float p0 = fexp2(sacc[n][0] - mrun);
      float p1 = fexp2(sacc[n][1] - mrun);
      float p2 = fexp2(sacc[n][2] - mrun);
      float p3 = fexp2(sacc[n][3] - mrun);
      rs += (p0 + p1) + (p2 + p3);
      pmax = fmaxf(pmax, fmaxf(fmaxf(p0, p1), fmaxf(p2, p3)));
      uint2 wv;
      wv.x = cvt_pk_bf16(p0, p1);
      wv.y = cvt_pk_bf16(p2, p3);
      *(uint2*)(pw + pso[n]) = wv;
    }
    rs += __shfl_xor(rs, 16);
    rs += __shfl_xor(rs, 32);
    lrun += rs;

    // ---- PV: O^T += V * P   (oacc[dn]: d = dn*16+lh*4+r, q = l15)
    __builtin_amdgcn_s_setprio(1);
#pragma unroll
    for (int kk = 0; kk < 2; ++kk) {
      bf16x8 pf = *(const bf16x8*)(pw + kk * 512 + lb);
#pragma unroll
      for (int dn = 0; dn < 4; ++dn) {
        bf16x8 vf = *(const bf16x8*)(vb + (dn * 2 + kk) * 512 + lb);
        oacc[dn] = __builtin_amdgcn_mfma_f32_16x16x32_bf16(vf, pf, oacc[dn], 0, 0, 0);
      }
    }
    __builtin_amdgcn_s_setprio(0);

    // ---- deferred max maintenance (post-PV, off critical path)
    pmax = fmaxf(pmax, __shfl_xor(pmax, 16));
    pmax = fmaxf(pmax, __shfl_xor(pmax, 32));
    if (!__all(pmax <= 256.0f)) {
      float sf = __frcp_rn(pmax);
      float lg; asm("v_log_f32 %0, %1" : "=v"(lg) : "v"(pmax));
      lrun *= sf;
#pragma unroll
      for (int dn = 0; dn < 4; ++dn)
#pragma unroll
        for (int r = 0; r < 4; ++r) oacc[dn][r] *= sf;
      mrun += lg;
    }

    asm volatile("s_waitcnt vmcnt(0)" ::: "memory");
    __syncthreads();
  }

  // ---- epilogue: normalize (state lane-local), transpose via LDS bounce ----
  {
    float inv = 1.f / lrun;
#pragma unroll
    for (int dn = 0; dn < 4; ++dn) {
      int d0 = dn * 16 + lh * 4;
      uint2 wv;
      wv.x = cvt_pk_bf16(oacc[dn][0] * inv, oacc[dn][1] * inv);
      wv.y = cvt_pk_bf16(oacc[dn][2] * inv, oacc[dn][3] * inv);
      *(uint2*)(pw + l15 * 64 + ((d0 + l15 * 8) & 63)) = wv;
    }
    asm volatile("s_waitcnt lgkmcnt(0)" ::: "memory");
    __builtin_amdgcn_sched_barrier(0);
    const int q  = lane >> 2;                // 16 rows x 4 d-chunks of 16
    const int dc = (lane & 3) * 16;
#pragma unroll
    for (int half = 0; half < 2; ++half) {
      int ds = dc + half * 8;
      i32x4 v = *(const i32x4*)(pw + q * 64 + ((ds + q * 8) & 63));
      *(i32x4*)(Oa + (size_t)(q0 + wave * 16 + q) * DM + h * HD + ds) = v;  // full 16B (8 elems)
    }
  }
}

extern "C" void kernel_launch(void* const* d_in, const int* in_sizes, int n_in,
                              void* d_out, int out_size, void* d_ws, size_t ws_size,
                              hipStream_t stream)
{
  const float* x     = (const float*)d_in[0];
  const float* wqkv  = (const float*)d_in[1];
  const float* wproj = (const float*)d_in[2];
  float* out = (float*)d_out;

  char* ws = (char*)d_ws;
  size_t off = 0;
  u16* xb   = (u16*)(ws + off); off += (size_t)TSEQ * DM * 2;
  u16* wqb  = (u16*)(ws + off); off += (size_t)NQKV * DM * 2;
  u16* wpb  = (u16*)(ws + off); off += (size_t)DM * DM * 2;
  u16* qkvb = (u16*)(ws + off); off += (size_t)TSEQ * NQKV * 2;
  u16* Qb   = (u16*)(ws + off); off += (size_t)NH * TSEQ * HD * 2;
  u16* Kb   = (u16*)(ws + off); off += (size_t)NH * TSEQ * HD * 2;
  u16* Vb   = (u16*)(ws + off); off += (size_t)NH * TSEQ * HD * 2;
  u16* Ob   = (u16*)(ws + off); off += (size_t)TSEQ * DM * 2;
  float* sT = (float*)(ws + off); off += (size_t)TSEQ * 32 * 4;
  float* cT = (float*)(ws + off); off += (size_t)TSEQ * 32 * 4;

  const int ncast = N4X + N4Q + N4P;
  cast3_kernel<<<(ncast + 255) / 256, 256, 0, stream>>>(x, xb, wqkv, wqb, wproj, wpb);
  rope_table<<<(TSEQ * 32) / 256, 256, 0, stream>>>(sT, cT);

  gemm_bt<1><<<dim3(NQKV / 128, TSEQ / 128), 256, 0, stream>>>(xb, wqb, qkvb, TSEQ, NQKV, DM);

  rope_reorg<<<(TSEQ * NH * 32) / 256, 256, 0, stream>>>(qkvb, sT, cT, Qb, Kb, Vb);

  fattn<<<NH * 64, 256, 0, stream>>>(Qb, Kb, Vb, Ob);

  gemm_bt<0><<<dim3(DM / 128, TSEQ / 128), 256, 0, stream>>>(Ob, wpb, out, TSEQ, DM, DM);
}

// Round 8
// 171.295 us; speedup vs baseline: 1.1982x; 1.0493x over previous
//
#include <hip/hip_runtime.h>
#include <hip/hip_bf16.h>
#include <stdint.h>

#define TSEQ 4096
#define DM   1024
#define NH   16
#define HD   64
#define NQKV 3072

typedef unsigned short u16;
typedef unsigned int   u32;
typedef __attribute__((ext_vector_type(8)))  short bf16x8;
typedef __attribute__((ext_vector_type(4)))  float f32x4;
typedef __attribute__((ext_vector_type(4)))  int   i32x4;

static __device__ __forceinline__ u16 f2bf(float f) {
  u32 u = __float_as_uint(f);
  u32 r = (u + 0x7FFFu + ((u >> 16) & 1u)) >> 16;   // RNE
  return (u16)r;
}
static __device__ __forceinline__ float bf2f(u16 u) {
  return __uint_as_float(((u32)u) << 16);
}
static __device__ __forceinline__ u32 cvt_pk_bf16(float lo, float hi) {
  u32 r;
  asm("v_cvt_pk_bf16_f32 %0, %1, %2" : "=v"(r) : "v"(lo), "v"(hi));
  return r;
}
static __device__ __forceinline__ float fexp2(float x) {   // guaranteed v_exp_f32
  float r;
  asm("v_exp_f32 %0, %1" : "=v"(r) : "v"(x));
  return r;
}

#define GLL16(g, l) __builtin_amdgcn_global_load_lds( \
    (const __attribute__((address_space(1))) u32*)(g), \
    (__attribute__((address_space(3))) u32*)(l), 16, 0, 0)

// ---------------- fused cast fp32 -> bf16 for x, W_qkv, W_proj --------------
#define N4X  (TSEQ * DM / 4)
#define N4Q  (NQKV * DM / 4)
#define N4P  (DM * DM / 4)
__global__ void cast3_kernel(const float* __restrict__ x, u16* __restrict__ xo,
                             const float* __restrict__ wq, u16* __restrict__ wqo,
                             const float* __restrict__ wp, u16* __restrict__ wpo) {
  int i = blockIdx.x * 256 + threadIdx.x;
  const float* in; u16* out; int k;
  if (i < N4X)            { in = x;  out = xo;  k = i; }
  else if (i < N4X + N4Q) { in = wq; out = wqo; k = i - N4X; }
  else if (i < N4X + N4Q + N4P) { in = wp; out = wpo; k = i - N4X - N4Q; }
  else return;
  float4 v = ((const float4*)in)[k];
  ushort4 o;
  o.x = f2bf(v.x); o.y = f2bf(v.y); o.z = f2bf(v.z); o.w = f2bf(v.w);
  ((ushort4*)out)[k] = o;
}

// ---------------- RoPE sin/cos table [T][32] ----------------
__global__ void rope_table(float* __restrict__ sT, float* __restrict__ cT) {
  int i = blockIdx.x * 256 + threadIdx.x;   // t*32 + j
  int t = i >> 5, j = i & 31;
  float inv = exp2f((float)j * (-13.287712379549449f / 32.0f)); // 10000^(-j/32)
  float ang = (float)t * inv;
  sT[i] = sinf(ang);
  cT[i] = cosf(ang);
}

// ---------------- GEMM C[M,N] = A[M,K] * B[N,K]^T (bf16 in, fp32 acc) --------
template<int WRITE_BF16>
__global__ __launch_bounds__(256) void gemm_bt(const u16* __restrict__ A,
                                               const u16* __restrict__ B,
                                               void* __restrict__ Cout,
                                               int M, int N, int K)
{
  __shared__ __align__(16) u16 As[128 * 32];
  __shared__ __align__(16) u16 Bs[128 * 32];
  const int tid  = threadIdx.x;
  const int wave = tid >> 6, lane = tid & 63;
  const int l15  = lane & 15, lh = lane >> 4;
  const int wr   = wave >> 1, wc = wave & 1;

  const int nwg = gridDim.x * gridDim.y;
  int lin = blockIdx.y * gridDim.x + blockIdx.x;
  lin = (lin & 7) * (nwg >> 3) + (lin >> 3);          // nwg % 8 == 0
  const size_t bm = (size_t)(lin / gridDim.x);
  const size_t bn = (size_t)(lin % gridDim.x);

  f32x4 acc[4][4] = {};

  const u16* Ab = A + bm * 128 * (size_t)K;
  const u16* Bb = B + bn * 128 * (size_t)K;

  for (int k0 = 0; k0 < K; k0 += 32) {
    __syncthreads();
#pragma unroll
    for (int j = 0; j < 2; ++j) {
      const int ch = j * 4 + wave;            // 8 chunks of 1024B per tile
      const int e  = ch * 512 + lane * 8;     // element within tile (row-major [128][32])
      const int r  = e >> 5, c = e & 31;
      GLL16(Ab + (size_t)r * K + k0 + c, As + ch * 512);
      GLL16(Bb + (size_t)r * K + k0 + c, Bs + ch * 512);
    }
    asm volatile("s_waitcnt vmcnt(0)" ::: "memory");
    __syncthreads();

    bf16x8 af[4], bfr[4];
#pragma unroll
    for (int m = 0; m < 4; ++m)
      af[m] = *(const bf16x8*)(As + (wr * 64 + m * 16 + l15) * 32 + lh * 8);
#pragma unroll
    for (int n = 0; n < 4; ++n)
      bfr[n] = *(const bf16x8*)(Bs + (wc * 64 + n * 16 + l15) * 32 + lh * 8);
#pragma unroll
    for (int m = 0; m < 4; ++m)
#pragma unroll
      for (int n = 0; n < 4; ++n)
        acc[m][n] = __builtin_amdgcn_mfma_f32_16x16x32_bf16(af[m], bfr[n], acc[m][n], 0, 0, 0);
  }

#pragma unroll
  for (int m = 0; m < 4; ++m)
#pragma unroll
    for (int n = 0; n < 4; ++n)
#pragma unroll
      for (int r = 0; r < 4; ++r) {
        size_t row = bm * 128 + wr * 64 + m * 16 + lh * 4 + r;
        size_t col = bn * 128 + wc * 64 + n * 16 + l15;
        float v = acc[m][n][r];
        if (WRITE_BF16) ((u16*)Cout)[row * N + col] = f2bf(v);
        else            ((float*)Cout)[row * N + col] = v;
      }
}

// ---------------- RoPE + head-split into 16x16-MFMA-fragment layouts --------
// Q,K (B/A-frag, 16 t-rows x 32 d): idx = (((h*256+(t>>4))*2+(d>>5))*64 + (t&15)+((d>>3)&3)*16)*8 + (d&7)
// V^T (A-frag, 16 d-rows x 32 kv):  idx = ((((h*64+(t>>6))*4+(d>>4))*2+((t>>5)&1))*64 + (d&15)+((t>>3)&3)*16)*8 + (t&7)
__global__ void rope_reorg(const u16* __restrict__ qkv,
                           const float* __restrict__ sT, const float* __restrict__ cT,
                           u16* __restrict__ Qo, u16* __restrict__ Ko, u16* __restrict__ Vo)
{
  int idx = blockIdx.x * 256 + threadIdx.x;   // (t*16 + h)*32 + j
  int j = idx & 31;
  int h = (idx >> 5) & 15;
  int t = idx >> 9;
  const float QSC = 0.125f * 1.4426950408889634f;  // 1/sqrt(64) * log2(e)
  float s = sT[t * 32 + j], c = cT[t * 32 + j];
  const u16* row = qkv + (size_t)t * NQKV + h * HD;
  float q1 = bf2f(row[j]),        q2 = bf2f(row[j + 32]);
  float k1 = bf2f(row[DM + j]),   k2 = bf2f(row[DM + j + 32]);
  float qa = (q1 * c - q2 * s) * QSC, qb2 = (q2 * c + q1 * s) * QSC;
  float ka = k1 * c - k2 * s,         kb2 = k2 * c + k1 * s;

  int d0 = j, d1 = j + 32;
  size_t qk0 = ((((size_t)h * 256 + (t >> 4)) * 2 + (d0 >> 5)) * 64 +
                (t & 15) + ((d0 >> 3) & 3) * 16) * 8 + (d0 & 7);
  size_t qk1 = ((((size_t)h * 256 + (t >> 4)) * 2 + (d1 >> 5)) * 64 +
                (t & 15) + ((d1 >> 3) & 3) * 16) * 8 + (d1 & 7);
  Qo[qk0] = f2bf(qa);  Qo[qk1] = f2bf(qb2);
  Ko[qk0] = f2bf(ka);  Ko[qk1] = f2bf(kb2);

  size_t vt = (size_t)((t >> 5) & 1) * 64 + ((t >> 3) & 3) * 16;  // kv-chunk+colgrp part
  size_t vbase = (((size_t)h * 64 + (t >> 6)) * 8) * 64;          // 8 blocks per kv-tile
  size_t v0 = (vbase + (size_t)(d0 >> 4) * 128 + vt + (d0 & 15)) * 8 + (t & 7);
  size_t v1 = (vbase + (size_t)(d1 >> 4) * 128 + vt + (d1 & 15)) * 8 + (t & 7);
  Vo[v0] = row[2 * DM + j];
  Vo[v1] = row[2 * DM + j + 32];
}

// ---------------- causal flash attention ----------------
// grid 16 heads x 32 q-tile PAIRS (512 blocks), 4 waves x 16 q-rows, 2 phases
// per block {pr, 63-pr} -> uniform 66 kv-steps. S^T = mfma(K,Q): q = lane&15,
// softmax state lane-local. O^T = mfma(V,P): same layout.
// K/V: global_load_lds (frag-linear, conflict-free), dbuf, 1 barrier/step.
// Steady state has ZERO cross-lane ops: -mrun folded into MFMA C-init,
// lane-partial lrun (reduced in epilogue), pmax check via __all only.
__global__ __launch_bounds__(256) void fattn(const u16* __restrict__ Qf,
                                             const u16* __restrict__ Kf,
                                             const u16* __restrict__ Vf,
                                             u16* __restrict__ Oa)
{
  __shared__ __align__(16) u16 Ks[2][4096];
  __shared__ __align__(16) u16 Vs[2][4096];
  __shared__ __align__(16) u16 Ps[4][1024];

  const int bid = blockIdx.x;
  const int h   = bid & (NH - 1);            // h, h+8 share XCD (bid&7)
  const int pr  = bid >> 4;                  // 0..31
  const int tid = threadIdx.x;
  const int wave = tid >> 6, lane = tid & 63;
  const int l15 = lane & 15, lh = lane >> 4;
  const int qg  = wave * 16 + l15;           // local q row this lane owns
  const int lb  = lane * 8;                  // linear fragment offset (elems)

  const size_t hbase = (size_t)h * (TSEQ * HD);
  const u16* kg = Kf + hbase;
  const u16* vg = Vf + hbase;

  // P store offsets (elems), per n-tile: frag-linear B layout
  u16* const pw = &Ps[wave][0];
  int pso[4];
#pragma unroll
  for (int n = 0; n < 4; ++n)
    pso[n] = (n >> 1) * 512 + (((2 * n + (lh >> 1)) & 3) * 16 + l15) * 8 + (lh & 1) * 4;

  for (int ph = 0; ph < 2; ++ph) {
    const int qt  = ph ? (63 - pr) : pr;
    const int q0  = qt * 64;
    const int nkv = qt + 1;

    // Q fragments (B-operand)
    bf16x8 qf0, qf1;
    {
      const u16* qp = Qf + hbase + (size_t)(q0 / 16 + wave) * 1024;
      qf0 = *(const bf16x8*)(qp + lb);
      qf1 = *(const bf16x8*)(qp + 512 + lb);
    }

    f32x4 oacc[4] = {};
    float mrun = 0.f, lrunp = 0.f;           // lrunp is LANE-PARTIAL

    // prologue: stage tile 0 -> buf 0
#pragma unroll
    for (int c = 0; c < 2; ++c) {
      GLL16(kg + tid * 8 + c * 2048, &Ks[0][tid * 8 + c * 2048]);
      GLL16(vg + tid * 8 + c * 2048, &Vs[0][tid * 8 + c * 2048]);
    }
    asm volatile("s_waitcnt vmcnt(0)" ::: "memory");
    __syncthreads();

    for (int kt = 0; kt < nkv; ++kt) {
      const int cur = kt & 1;
      if (kt + 1 < nkv) {                    // stage next tile during compute
        const u16* kg2 = kg + (size_t)(kt + 1) * 4096;
        const u16* vg2 = vg + (size_t)(kt + 1) * 4096;
#pragma unroll
        for (int c = 0; c < 2; ++c) {
          GLL16(kg2 + tid * 8 + c * 2048, &Ks[cur ^ 1][tid * 8 + c * 2048]);
          GLL16(vg2 + tid * 8 + c * 2048, &Vs[cur ^ 1][tid * 8 + c * 2048]);
        }
      }
      const u16* kb = Ks[cur];
      const u16* vb = Vs[cur];

      // ---- S^T = mfma(K,Q) with C-init = -mrun (kt>0): exp input is ready
      const float mz = (kt == 0) ? 0.f : -mrun;
      f32x4 sacc[4];
      __builtin_amdgcn_s_setprio(1);
#pragma unroll
      for (int n = 0; n < 4; ++n) {
        bf16x8 kf0 = *(const bf16x8*)(kb + (n * 2 + 0) * 512 + lb);
        bf16x8 kf1 = *(const bf16x8*)(kb + (n * 2 + 1) * 512 + lb);
        f32x4 z = {mz, mz, mz, mz};
        sacc[n] = __builtin_amdgcn_mfma_f32_16x16x32_bf16(kf0, qf0, z, 0, 0, 0);
        sacc[n] = __builtin_amdgcn_mfma_f32_16x16x32_bf16(kf1, qf1, sacc[n], 0, 0, 0);
      }
      __builtin_amdgcn_s_setprio(0);

      if (kt == qt) {                        // diagonal tile: mask kv > q
#pragma unroll
        for (int n = 0; n < 4; ++n)
#pragma unroll
          for (int r = 0; r < 4; ++r)
            if (n * 16 + lh * 4 + r > qg) sacc[n][r] = -3.0e38f;
      }

      if (kt == 0) {                         // tile 0: real row max, then bias
        float tm = fmaxf(fmaxf(sacc[0][0], sacc[0][1]), fmaxf(sacc[0][2], sacc[0][3]));
#pragma unroll
        for (int n = 1; n < 4; ++n)
          tm = fmaxf(tm, fmaxf(fmaxf(sacc[n][0], sacc[n][1]), fmaxf(sacc[n][2], sacc[n][3])));
        tm = fmaxf(tm, __shfl_xor(tm, 16));
        tm = fmaxf(tm, __shfl_xor(tm, 32));
        mrun = tm;
#pragma unroll
        for (int n = 0; n < 4; ++n)
#pragma unroll
          for (int r = 0; r < 4; ++r) sacc[n][r] -= mrun;
      }

      // ---- exp + lane-partial sum/max (NO cross-lane ops)
      float rs = 0.f, pmax = 0.f;
#pragma unroll
      for (int n = 0; n < 4; ++n) {
        float p0 = fexp2(sacc[n][0]);
        float p1 = fexp2(sacc[n][1]);
        float p2 = fexp2(sacc[n][2]);
        float p3 = fexp2(sacc[n][3]);
        rs += (p0 + p1) + (p2 + p3);
        pmax = fmaxf(pmax, fmaxf(fmaxf(p0, p1), fmaxf(p2, p3)));
        uint2 wv;
        wv.x = cvt_pk_bf16(p0, p1);
        wv.y = cvt_pk_bf16(p2, p3);
        *(uint2*)(pw + pso[n]) = wv;
      }
      lrunp += rs;

      // ---- PV: O^T += V * P   (oacc[dn]: d = dn*16+lh*4+r, q = l15)
      __builtin_amdgcn_s_setprio(1);
#pragma unroll
      for (int kk = 0; kk < 2; ++kk) {
        bf16x8 pf = *(const bf16x8*)(pw + kk * 512 + lb);
#pragma unroll
        for (int dn = 0; dn < 4; ++dn) {
          bf16x8 vf = *(const bf16x8*)(vb + (dn * 2 + kk) * 512 + lb);
          oacc[dn] = __builtin_amdgcn_mfma_f32_16x16x32_bf16(vf, pf, oacc[dn], 0, 0, 0);
        }
      }
      __builtin_amdgcn_s_setprio(0);

      // ---- deferred-max maintenance: vcc-only check; shuffles only if rare hit
      if (!__all(pmax <= 256.0f)) {
        pmax = fmaxf(pmax, __shfl_xor(pmax, 16));
        pmax = fmaxf(pmax, __shfl_xor(pmax, 32));
        float sf = __frcp_rn(pmax);
        float lg; asm("v_log_f32 %0, %1" : "=v"(lg) : "v"(pmax));
        lrunp *= sf;
#pragma unroll
        for (int dn = 0; dn < 4; ++dn)
#pragma unroll
          for (int r = 0; r < 4; ++r) oacc[dn][r] *= sf;
        mrun += lg;
      }

      asm volatile("s_waitcnt vmcnt(0)" ::: "memory");
      __syncthreads();
    }

    // ---- epilogue: reduce lane-partial lrun, normalize, LDS bounce, store
    {
      float lr = lrunp;
      lr += __shfl_xor(lr, 16);
      lr += __shfl_xor(lr, 32);
      float inv = 1.f / lr;
#pragma unroll
      for (int dn = 0; dn < 4; ++dn) {
        int d0 = dn * 16 + lh * 4;
        uint2 wv;
        wv.x = cvt_pk_bf16(oacc[dn][0] * inv, oacc[dn][1] * inv);
        wv.y = cvt_pk_bf16(oacc[dn][2] * inv, oacc[dn][3] * inv);
        *(uint2*)(pw + l15 * 64 + ((d0 + l15 * 8) & 63)) = wv;
      }
      asm volatile("s_waitcnt lgkmcnt(0)" ::: "memory");
      __builtin_amdgcn_sched_barrier(0);
      const int q  = lane >> 2;              // 16 rows x 4 d-chunks of 16
      const int dc = (lane & 3) * 16;
#pragma unroll
      for (int half = 0; half < 2; ++half) {
        int ds = dc + half * 8;
        i32x4 v = *(const i32x4*)(pw + q * 64 + ((ds + q * 8) & 63));
        *(i32x4*)(Oa + (size_t)(q0 + wave * 16 + q) * DM + h * HD + ds) = v;
      }
    }
  }
}

extern "C" void kernel_launch(void* const* d_in, const int* in_sizes, int n_in,
                              void* d_out, int out_size, void* d_ws, size_t ws_size,
                              hipStream_t stream)
{
  const float* x     = (const float*)d_in[0];
  const float* wqkv  = (const float*)d_in[1];
  const float* wproj = (const float*)d_in[2];
  float* out = (float*)d_out;

  char* ws = (char*)d_ws;
  size_t off = 0;
  u16* xb   = (u16*)(ws + off); off += (size_t)TSEQ * DM * 2;
  u16* wqb  = (u16*)(ws + off); off += (size_t)NQKV * DM * 2;
  u16* wpb  = (u16*)(ws + off); off += (size_t)DM * DM * 2;
  u16* qkvb = (u16*)(ws + off); off += (size_t)TSEQ * NQKV * 2;
  u16* Qb   = (u16*)(ws + off); off += (size_t)NH * TSEQ * HD * 2;
  u16* Kb   = (u16*)(ws + off); off += (size_t)NH * TSEQ * HD * 2;
  u16* Vb   = (u16*)(ws + off); off += (size_t)NH * TSEQ * HD * 2;
  u16* Ob   = (u16*)(ws + off); off += (size_t)TSEQ * DM * 2;
  float* sT = (float*)(ws + off); off += (size_t)TSEQ * 32 * 4;
  float* cT = (float*)(ws + off); off += (size_t)TSEQ * 32 * 4;

  const int ncast = N4X + N4Q + N4P;
  cast3_kernel<<<(ncast + 255) / 256, 256, 0, stream>>>(x, xb, wqkv, wqb, wproj, wpb);
  rope_table<<<(TSEQ * 32) / 256, 256, 0, stream>>>(sT, cT);

  gemm_bt<1><<<dim3(NQKV / 128, TSEQ / 128), 256, 0, stream>>>(xb, wqb, qkvb, TSEQ, NQKV, DM);

  rope_reorg<<<(TSEQ * NH * 32) / 256, 256, 0, stream>>>(qkvb, sT, cT, Qb, Kb, Vb);

  fattn<<<NH * 32, 256, 0, stream>>>(Qb, Kb, Vb, Ob);

  gemm_bt<0><<<dim3(DM / 128, TSEQ / 128), 256, 0, stream>>>(Ob, wpb, out, TSEQ, DM, DM);
}

// Round 9
// 165.897 us; speedup vs baseline: 1.2371x; 1.0325x over previous
//
#include <hip/hip_runtime.h>
#include <hip/hip_bf16.h>
#include <stdint.h>

#define TSEQ 4096
#define DM   1024
#define NH   16
#define HD   64
#define NQKV 3072

typedef unsigned short u16;
typedef unsigned int   u32;
typedef __attribute__((ext_vector_type(8)))  short bf16x8;
typedef __attribute__((ext_vector_type(4)))  float f32x4;
typedef __attribute__((ext_vector_type(4)))  int   i32x4;

static __device__ __forceinline__ u16 f2bf(float f) {
  u32 u = __float_as_uint(f);
  u32 r = (u + 0x7FFFu + ((u >> 16) & 1u)) >> 16;   // RNE
  return (u16)r;
}
static __device__ __forceinline__ float bf2f(u16 u) {
  return __uint_as_float(((u32)u) << 16);
}
static __device__ __forceinline__ u32 cvt_pk_bf16(float lo, float hi) {
  u32 r;
  asm("v_cvt_pk_bf16_f32 %0, %1, %2" : "=v"(r) : "v"(lo), "v"(hi));
  return r;
}
static __device__ __forceinline__ float fexp2(float x) {   // guaranteed v_exp_f32
  float r;
  asm("v_exp_f32 %0, %1" : "=v"(r) : "v"(x));
  return r;
}

#define GLL16(g, l) __builtin_amdgcn_global_load_lds( \
    (const __attribute__((address_space(1))) u32*)(g), \
    (__attribute__((address_space(3))) u32*)(l), 16, 0, 0)

// ---------------- fused cast fp32 -> bf16 for x, W_qkv, W_proj --------------
#define N4X  (TSEQ * DM / 4)
#define N4Q  (NQKV * DM / 4)
#define N4P  (DM * DM / 4)
__global__ void cast3_kernel(const float* __restrict__ x, u16* __restrict__ xo,
                             const float* __restrict__ wq, u16* __restrict__ wqo,
                             const float* __restrict__ wp, u16* __restrict__ wpo) {
  int i = blockIdx.x * 256 + threadIdx.x;
  const float* in; u16* out; int k;
  if (i < N4X)            { in = x;  out = xo;  k = i; }
  else if (i < N4X + N4Q) { in = wq; out = wqo; k = i - N4X; }
  else if (i < N4X + N4Q + N4P) { in = wp; out = wpo; k = i - N4X - N4Q; }
  else return;
  float4 v = ((const float4*)in)[k];
  ushort4 o;
  o.x = f2bf(v.x); o.y = f2bf(v.y); o.z = f2bf(v.z); o.w = f2bf(v.w);
  ((ushort4*)out)[k] = o;
}

// ---------------- RoPE sin/cos table [T][32] ----------------
__global__ void rope_table(float* __restrict__ sT, float* __restrict__ cT) {
  int i = blockIdx.x * 256 + threadIdx.x;   // t*32 + j
  int t = i >> 5, j = i & 31;
  float inv = exp2f((float)j * (-13.287712379549449f / 32.0f)); // 10000^(-j/32)
  float ang = (float)t * inv;
  sT[i] = sinf(ang);
  cT[i] = cosf(ang);
}

// ---------------- GEMM C[M,N] = A[M,K] * B[N,K]^T (bf16 in, fp32 acc) --------
template<int WRITE_BF16>
__global__ __launch_bounds__(256) void gemm_bt(const u16* __restrict__ A,
                                               const u16* __restrict__ B,
                                               void* __restrict__ Cout,
                                               int M, int N, int K)
{
  __shared__ __align__(16) u16 As[128 * 32];
  __shared__ __align__(16) u16 Bs[128 * 32];
  const int tid  = threadIdx.x;
  const int wave = tid >> 6, lane = tid & 63;
  const int l15  = lane & 15, lh = lane >> 4;
  const int wr   = wave >> 1, wc = wave & 1;

  const int nwg = gridDim.x * gridDim.y;
  int lin = blockIdx.y * gridDim.x + blockIdx.x;
  lin = (lin & 7) * (nwg >> 3) + (lin >> 3);          // nwg % 8 == 0
  const size_t bm = (size_t)(lin / gridDim.x);
  const size_t bn = (size_t)(lin % gridDim.x);

  f32x4 acc[4][4] = {};

  const u16* Ab = A + bm * 128 * (size_t)K;
  const u16* Bb = B + bn * 128 * (size_t)K;

  for (int k0 = 0; k0 < K; k0 += 32) {
    __syncthreads();
#pragma unroll
    for (int j = 0; j < 2; ++j) {
      const int ch = j * 4 + wave;            // 8 chunks of 1024B per tile
      const int e  = ch * 512 + lane * 8;     // element within tile (row-major [128][32])
      const int r  = e >> 5, c = e & 31;
      GLL16(Ab + (size_t)r * K + k0 + c, As + ch * 512);
      GLL16(Bb + (size_t)r * K + k0 + c, Bs + ch * 512);
    }
    asm volatile("s_waitcnt vmcnt(0)" ::: "memory");
    __syncthreads();

    bf16x8 af[4], bfr[4];
#pragma unroll
    for (int m = 0; m < 4; ++m)
      af[m] = *(const bf16x8*)(As + (wr * 64 + m * 16 + l15) * 32 + lh * 8);
#pragma unroll
    for (int n = 0; n < 4; ++n)
      bfr[n] = *(const bf16x8*)(Bs + (wc * 64 + n * 16 + l15) * 32 + lh * 8);
#pragma unroll
    for (int m = 0; m < 4; ++m)
#pragma unroll
      for (int n = 0; n < 4; ++n)
        acc[m][n] = __builtin_amdgcn_mfma_f32_16x16x32_bf16(af[m], bfr[n], acc[m][n], 0, 0, 0);
  }

#pragma unroll
  for (int m = 0; m < 4; ++m)
#pragma unroll
    for (int n = 0; n < 4; ++n)
#pragma unroll
      for (int r = 0; r < 4; ++r) {
        size_t row = bm * 128 + wr * 64 + m * 16 + lh * 4 + r;
        size_t col = bn * 128 + wc * 64 + n * 16 + l15;
        float v = acc[m][n][r];
        if (WRITE_BF16) ((u16*)Cout)[row * N + col] = f2bf(v);
        else            ((float*)Cout)[row * N + col] = v;
      }
}

// ---------------- RoPE + head-split into 16x16-MFMA-fragment layouts --------
// Q,K (B/A-frag, 16 t-rows x 32 d): idx = (((h*256+(t>>4))*2+(d>>5))*64 + (t&15)+((d>>3)&3)*16)*8 + (d&7)
// V^T (A-frag, 16 d-rows x 32 kv):  idx = ((((h*64+(t>>6))*4+(d>>4))*2+((t>>5)&1))*64 + (d&15)+((t>>3)&3)*16)*8 + (t&7)
__global__ void rope_reorg(const u16* __restrict__ qkv,
                           const float* __restrict__ sT, const float* __restrict__ cT,
                           u16* __restrict__ Qo, u16* __restrict__ Ko, u16* __restrict__ Vo)
{
  int idx = blockIdx.x * 256 + threadIdx.x;   // (t*16 + h)*32 + j
  int j = idx & 31;
  int h = (idx >> 5) & 15;
  int t = idx >> 9;
  const float QSC = 0.125f * 1.4426950408889634f;  // 1/sqrt(64) * log2(e)
  float s = sT[t * 32 + j], c = cT[t * 32 + j];
  const u16* row = qkv + (size_t)t * NQKV + h * HD;
  float q1 = bf2f(row[j]),        q2 = bf2f(row[j + 32]);
  float k1 = bf2f(row[DM + j]),   k2 = bf2f(row[DM + j + 32]);
  float qa = (q1 * c - q2 * s) * QSC, qb2 = (q2 * c + q1 * s) * QSC;
  float ka = k1 * c - k2 * s,         kb2 = k2 * c + k1 * s;

  int d0 = j, d1 = j + 32;
  size_t qk0 = ((((size_t)h * 256 + (t >> 4)) * 2 + (d0 >> 5)) * 64 +
                (t & 15) + ((d0 >> 3) & 3) * 16) * 8 + (d0 & 7);
  size_t qk1 = ((((size_t)h * 256 + (t >> 4)) * 2 + (d1 >> 5)) * 64 +
                (t & 15) + ((d1 >> 3) & 3) * 16) * 8 + (d1 & 7);
  Qo[qk0] = f2bf(qa);  Qo[qk1] = f2bf(qb2);
  Ko[qk0] = f2bf(ka);  Ko[qk1] = f2bf(kb2);

  size_t vt = (size_t)((t >> 5) & 1) * 64 + ((t >> 3) & 3) * 16;  // kv-chunk+colgrp part
  size_t vbase = (((size_t)h * 64 + (t >> 6)) * 8) * 64;          // 8 blocks per kv-tile
  size_t v0 = (vbase + (size_t)(d0 >> 4) * 128 + vt + (d0 & 15)) * 8 + (t & 7);
  size_t v1 = (vbase + (size_t)(d1 >> 4) * 128 + vt + (d1 & 15)) * 8 + (t & 7);
  Vo[v0] = row[2 * DM + j];
  Vo[v1] = row[2 * DM + j + 32];
}

// ---------------- causal flash attention, kv-split G=2 ----------------
// grid 16 heads x 32 pairs x 2 kv-groups = 1024 blocks (4/CU -> 50% occ cap).
// Block: phases {qt=pr, qt=63-pr}, kv tiles [kt0, kt1) of its group (~33 steps).
// Inner loop identical to R7 (frag-linear gload_lds staging, dbuf, 1 barrier,
// zero cross-lane steady state, deferred max). Epilogue stores NORMALIZED
// partial O (bf16, row-major) + per-q (m, l) f32; merge_o combines groups.
__global__ __launch_bounds__(256) void fattn(const u16* __restrict__ Qf,
                                             const u16* __restrict__ Kf,
                                             const u16* __restrict__ Vf,
                                             u16* __restrict__ Opart,
                                             float2* __restrict__ lmb)
{
  __shared__ __align__(16) u16 Ks[2][4096];
  __shared__ __align__(16) u16 Vs[2][4096];
  __shared__ __align__(16) u16 Ps[4][1024];

  const int bid = blockIdx.x;
  const int h   = bid & (NH - 1);            // h, h+8 share XCD (bid&7)
  const int g   = (bid >> 4) & 1;            // kv group
  const int pr  = bid >> 5;                  // 0..31
  const int tid = threadIdx.x;
  const int wave = tid >> 6, lane = tid & 63;
  const int l15 = lane & 15, lh = lane >> 4;
  const int qg  = wave * 16 + l15;           // local q row this lane owns
  const int lb  = lane * 8;                  // linear fragment offset (elems)

  const size_t hbase = (size_t)h * (TSEQ * HD);
  const u16* kg = Kf + hbase;
  const u16* vg = Vf + hbase;
  u16* const Og = Opart + (size_t)g * (TSEQ * DM);

  // P store offsets (elems), per n-tile: frag-linear B layout
  u16* const pw = &Ps[wave][0];
  int pso[4];
#pragma unroll
  for (int n = 0; n < 4; ++n)
    pso[n] = (n >> 1) * 512 + (((2 * n + (lh >> 1)) & 3) * 16 + l15) * 8 + (lh & 1) * 4;

  for (int ph = 0; ph < 2; ++ph) {
    const int qt  = ph ? (63 - pr) : pr;
    const int q0  = qt * 64;
    const int nkv = qt + 1;
    const int kt0 = g ? ((nkv + 1) >> 1) : 0;
    const int kt1 = g ? nkv : ((nkv + 1) >> 1);

    f32x4 oacc[4] = {};
    float mrun = 0.f, lrunp = 0.f;           // lrunp is LANE-PARTIAL

    if (kt0 < kt1) {
      // Q fragments (B-operand)
      bf16x8 qf0, qf1;
      {
        const u16* qp = Qf + hbase + (size_t)(q0 / 16 + wave) * 1024;
        qf0 = *(const bf16x8*)(qp + lb);
        qf1 = *(const bf16x8*)(qp + 512 + lb);
      }

      // prologue: stage tile kt0 -> buf 0
#pragma unroll
      for (int c = 0; c < 2; ++c) {
        GLL16(kg + (size_t)kt0 * 4096 + tid * 8 + c * 2048, &Ks[0][tid * 8 + c * 2048]);
        GLL16(vg + (size_t)kt0 * 4096 + tid * 8 + c * 2048, &Vs[0][tid * 8 + c * 2048]);
      }
      asm volatile("s_waitcnt vmcnt(0)" ::: "memory");
      __syncthreads();

      for (int kt = kt0; kt < kt1; ++kt) {
        const int cur = (kt - kt0) & 1;
        if (kt + 1 < kt1) {                  // stage next tile during compute
          const u16* kg2 = kg + (size_t)(kt + 1) * 4096;
          const u16* vg2 = vg + (size_t)(kt + 1) * 4096;
#pragma unroll
          for (int c = 0; c < 2; ++c) {
            GLL16(kg2 + tid * 8 + c * 2048, &Ks[cur ^ 1][tid * 8 + c * 2048]);
            GLL16(vg2 + tid * 8 + c * 2048, &Vs[cur ^ 1][tid * 8 + c * 2048]);
          }
        }
        const u16* kb = Ks[cur];
        const u16* vb = Vs[cur];

        // ---- S^T = mfma(K,Q) with C-init = -mrun (kt>kt0): exp input ready
        const float mz = (kt == kt0) ? 0.f : -mrun;
        f32x4 sacc[4];
        __builtin_amdgcn_s_setprio(1);
#pragma unroll
        for (int n = 0; n < 4; ++n) {
          bf16x8 kf0 = *(const bf16x8*)(kb + (n * 2 + 0) * 512 + lb);
          bf16x8 kf1 = *(const bf16x8*)(kb + (n * 2 + 1) * 512 + lb);
          f32x4 z = {mz, mz, mz, mz};
          sacc[n] = __builtin_amdgcn_mfma_f32_16x16x32_bf16(kf0, qf0, z, 0, 0, 0);
          sacc[n] = __builtin_amdgcn_mfma_f32_16x16x32_bf16(kf1, qf1, sacc[n], 0, 0, 0);
        }
        __builtin_amdgcn_s_setprio(0);

        if (kt == qt) {                      // diagonal tile: mask kv > q
#pragma unroll
          for (int n = 0; n < 4; ++n)
#pragma unroll
            for (int r = 0; r < 4; ++r)
              if (n * 16 + lh * 4 + r > qg) sacc[n][r] = -3.0e38f;
        }

        if (kt == kt0) {                     // first tile: real row max, bias
          float tm = fmaxf(fmaxf(sacc[0][0], sacc[0][1]), fmaxf(sacc[0][2], sacc[0][3]));
#pragma unroll
          for (int n = 1; n < 4; ++n)
            tm = fmaxf(tm, fmaxf(fmaxf(sacc[n][0], sacc[n][1]), fmaxf(sacc[n][2], sacc[n][3])));
          tm = fmaxf(tm, __shfl_xor(tm, 16));
          tm = fmaxf(tm, __shfl_xor(tm, 32));
          mrun = tm;
#pragma unroll
          for (int n = 0; n < 4; ++n)
#pragma unroll
            for (int r = 0; r < 4; ++r) sacc[n][r] -= mrun;
        }

        // ---- exp + lane-partial sum/max (NO cross-lane ops)
        float rs = 0.f, pmax = 0.f;
#pragma unroll
        for (int n = 0; n < 4; ++n) {
          float p0 = fexp2(sacc[n][0]);
          float p1 = fexp2(sacc[n][1]);
          float p2 = fexp2(sacc[n][2]);
          float p3 = fexp2(sacc[n][3]);
          rs += (p0 + p1) + (p2 + p3);
          pmax = fmaxf(pmax, fmaxf(fmaxf(p0, p1), fmaxf(p2, p3)));
          uint2 wv;
          wv.x = cvt_pk_bf16(p0, p1);
          wv.y = cvt_pk_bf16(p2, p3);
          *(uint2*)(pw + pso[n]) = wv;
        }
        lrunp += rs;

        // ---- PV: O^T += V * P   (oacc[dn]: d = dn*16+lh*4+r, q = l15)
        __builtin_amdgcn_s_setprio(1);
#pragma unroll
        for (int kk = 0; kk < 2; ++kk) {
          bf16x8 pf = *(const bf16x8*)(pw + kk * 512 + lb);
#pragma unroll
          for (int dn = 0; dn < 4; ++dn) {
            bf16x8 vf = *(const bf16x8*)(vb + (dn * 2 + kk) * 512 + lb);
            oacc[dn] = __builtin_amdgcn_mfma_f32_16x16x32_bf16(vf, pf, oacc[dn], 0, 0, 0);
          }
        }
        __builtin_amdgcn_s_setprio(0);

        // ---- deferred-max: vcc-only check; shuffles only on rare hit
        if (!__all(pmax <= 256.0f)) {
          pmax = fmaxf(pmax, __shfl_xor(pmax, 16));
          pmax = fmaxf(pmax, __shfl_xor(pmax, 32));
          float sf = __frcp_rn(pmax);
          float lg; asm("v_log_f32 %0, %1" : "=v"(lg) : "v"(pmax));
          lrunp *= sf;
#pragma unroll
          for (int dn = 0; dn < 4; ++dn)
#pragma unroll
            for (int r = 0; r < 4; ++r) oacc[dn][r] *= sf;
          mrun += lg;
        }

        asm volatile("s_waitcnt vmcnt(0)" ::: "memory");
        __syncthreads();
      }
    } else {
      mrun = -3.0e38f;                       // empty group: weight-0 sentinel
    }

    // ---- epilogue: reduce lane-partial l, store partial O + (m,l) ----
    {
      float lr = lrunp;
      lr += __shfl_xor(lr, 16);
      lr += __shfl_xor(lr, 32);

      if (kt0 < kt1) {
        float inv = 1.f / lr;
#pragma unroll
        for (int dn = 0; dn < 4; ++dn) {
          int d0 = dn * 16 + lh * 4;
          uint2 wv;
          wv.x = cvt_pk_bf16(oacc[dn][0] * inv, oacc[dn][1] * inv);
          wv.y = cvt_pk_bf16(oacc[dn][2] * inv, oacc[dn][3] * inv);
          *(uint2*)(pw + l15 * 64 + ((d0 + l15 * 8) & 63)) = wv;
        }
        asm volatile("s_waitcnt lgkmcnt(0)" ::: "memory");
        __builtin_amdgcn_sched_barrier(0);
        const int q  = lane >> 2;            // 16 rows x 4 d-chunks of 16
        const int dc = (lane & 3) * 16;
#pragma unroll
        for (int half = 0; half < 2; ++half) {
          int ds = dc + half * 8;
          i32x4 v = *(const i32x4*)(pw + q * 64 + ((ds + q * 8) & 63));
          *(i32x4*)(Og + (size_t)(q0 + wave * 16 + q) * DM + h * HD + ds) = v;
        }
      }
      if (lh == 0) {                         // per-q stats (m in log2 domain, l)
        float2 s; s.x = mrun; s.y = lr;
        lmb[((size_t)g * NH + h) * TSEQ + q0 + wave * 16 + l15] = s;
      }
    }
  }
}

// ---------------- merge the two kv-group partials ----------------
// O[q][h*64+d] = a0*O0 + a1*O1, a_g = 2^(m_g-m) * l_g / sum
__global__ void merge_o(const u16* __restrict__ Opart, const float2* __restrict__ lmb,
                        u16* __restrict__ Ob) {
  int i = blockIdx.x * 256 + threadIdx.x;    // [0, TSEQ*DM/8)
  int q  = i >> 7;
  int c8 = (i & 127) * 8;
  int h  = c8 >> 6;
  float2 s0 = lmb[(size_t)h * TSEQ + q];
  float2 s1 = lmb[(size_t)(NH + h) * TSEQ + q];
  float m  = fmaxf(s0.x, s1.x);
  float w0 = fexp2(s0.x - m) * s0.y;
  float w1 = fexp2(s1.x - m) * s1.y;
  float inv = 1.f / (w0 + w1);
  float a0 = w0 * inv, a1 = w1 * inv;
  size_t off = (size_t)q * DM + c8;
  i32x4 u0 = *(const i32x4*)(Opart + off);
  i32x4 u1 = *(const i32x4*)(Opart + (size_t)(TSEQ * DM) + off);
  const u16* p0 = (const u16*)&u0;
  const u16* p1 = (const u16*)&u1;
  union { u16 o[8]; i32x4 v; } r;
#pragma unroll
  for (int e = 0; e < 8; ++e)
    r.o[e] = f2bf(a0 * bf2f(p0[e]) + a1 * bf2f(p1[e]));
  *(i32x4*)(Ob + off) = r.v;
}

extern "C" void kernel_launch(void* const* d_in, const int* in_sizes, int n_in,
                              void* d_out, int out_size, void* d_ws, size_t ws_size,
                              hipStream_t stream)
{
  const float* x     = (const float*)d_in[0];
  const float* wqkv  = (const float*)d_in[1];
  const float* wproj = (const float*)d_in[2];
  float* out = (float*)d_out;

  char* ws = (char*)d_ws;
  size_t off = 0;
  u16* xb   = (u16*)(ws + off); off += (size_t)TSEQ * DM * 2;
  u16* wqb  = (u16*)(ws + off); off += (size_t)NQKV * DM * 2;
  u16* wpb  = (u16*)(ws + off); off += (size_t)DM * DM * 2;
  u16* qkvb = (u16*)(ws + off); off += (size_t)TSEQ * NQKV * 2;
  u16* Qb   = (u16*)(ws + off); off += (size_t)NH * TSEQ * HD * 2;
  u16* Kb   = (u16*)(ws + off); off += (size_t)NH * TSEQ * HD * 2;
  u16* Vb   = (u16*)(ws + off); off += (size_t)NH * TSEQ * HD * 2;
  u16* Ob   = (u16*)(ws + off); off += (size_t)TSEQ * DM * 2;
  float* sT = (float*)(ws + off); off += (size_t)TSEQ * 32 * 4;
  float* cT = (float*)(ws + off); off += (size_t)TSEQ * 32 * 4;

  // kv-split partials alias qkvb (dead after rope_reorg): 8MB + 8MB + 1MB < 24MB
  u16*    Opart = qkvb;
  float2* lmb   = (float2*)(qkvb + 2 * (size_t)TSEQ * DM);

  const int ncast = N4X + N4Q + N4P;
  cast3_kernel<<<(ncast + 255) / 256, 256, 0, stream>>>(x, xb, wqkv, wqb, wproj, wpb);
  rope_table<<<(TSEQ * 32) / 256, 256, 0, stream>>>(sT, cT);

  gemm_bt<1><<<dim3(NQKV / 128, TSEQ / 128), 256, 0, stream>>>(xb, wqb, qkvb, TSEQ, NQKV, DM);

  rope_reorg<<<(TSEQ * NH * 32) / 256, 256, 0, stream>>>(qkvb, sT, cT, Qb, Kb, Vb);

  fattn<<<NH * 64, 256, 0, stream>>>(Qb, Kb, Vb, Opart, lmb);

  merge_o<<<(TSEQ * DM / 8) / 256, 256, 0, stream>>>(Opart, lmb, Ob);

  gemm_bt<0><<<dim3(DM / 128, TSEQ / 128), 256, 0, stream>>>(Ob, wpb, out, TSEQ, DM, DM);
}